// Round 7
// baseline (670.984 us; speedup 1.0000x reference)
//
#include <hip/hip_runtime.h>
#include <hip/hip_bf16.h>
#include <math.h>

typedef __hip_bfloat16 bf16;
typedef short short8 __attribute__((ext_vector_type(8)));
typedef short short4v __attribute__((ext_vector_type(4)));
typedef float floatx4 __attribute__((ext_vector_type(4)));

constexpr int CB_ = 32;
constexpr int CT = 256;
constexpr int CF = 512;
constexpr int CN = 508;
constexpr int CM = 4;
constexpr int CT2 = 512;
constexpr int MROWS = CB_ * CF;  // 16384
constexpr int PADL = 528;       // xpT rows/batch: 0 pad, 1..512 live, 513 pad, rest slack

__device__ __forceinline__ float b2f(bf16 v) { return __bfloat162float(v); }
__device__ __forceinline__ bf16 f2b(float v) { return __float2bfloat16(v); }
__device__ __forceinline__ float silu_f(float x) { return x / (1.0f + expf(-x)); }
__device__ __forceinline__ float softplus_f(float x) {
    return fmaxf(x, 0.0f) + log1pf(expf(-fabsf(x)));
}

__device__ __forceinline__ void gl_lds16(const bf16* g, short* l) {
    __builtin_amdgcn_global_load_lds(
        (const __attribute__((address_space(1))) unsigned int*)(g),
        (__attribute__((address_space(3))) unsigned int*)(l), 16, 0, 0);
}

// ---- merged weight prepack: 8 matrices, W(KxN fp32) -> Wt(NxK bf16) ----
struct P8 { const float* s[8]; bf16* d[8]; };
__global__ __launch_bounds__(256) void prepack_all_kernel(P8 p) {
    const int Ks[8]   = {256, 256, 512, 512, 512, 512, 512, 256};
    const int Ns[8]   = {512, 512, 512, 256, 256, 512, 256, 256};
    const int zs[8]   = {3, 3, 3, 3, 3, 3, 3, 1};
    const int dstr[8] = {262144, 262144, 524288, 524288, 524288, 262144, 131072, 65536};
    int bid = blockIdx.x;
    int m = 0, acc = 0;
    for (m = 0; m < 8; m++) {
        int c = (Ns[m] >> 5) * (Ks[m] >> 5) * zs[m];
        if (bid < acc + c) break;
        acc += c;
    }
    int lid = bid - acc;
    int K = Ks[m], N = Ns[m];
    int tx = N >> 5, ty = K >> 5;
    int z = lid / (tx * ty), rem = lid % (tx * ty);
    int k0 = (rem / tx) * 32, n0 = (rem % tx) * 32;
    const float* s = p.s[m] + (size_t)z * K * N;
    bf16* d = p.d[m] + (size_t)z * dstr[m];
    __shared__ float Ts[32][33];
    for (int e = threadIdx.x; e < 1024; e += 256) {
        int r = e >> 5, c = e & 31;
        Ts[r][c] = s[(size_t)(k0 + r) * N + n0 + c];
    }
    __syncthreads();
    for (int e = threadIdx.x; e < 1024; e += 256) {
        int r = e >> 5, c = e & 31;
        d[(size_t)(n0 + r) * K + k0 + c] = f2b(Ts[c][r]);
    }
}

// ---- conv weight pack + xpT pad-row zero (merged) ----
constexpr int CONVN = 3 * 3 * 512 * 512;  // 2359296
__global__ void convpack_kernel(const float* __restrict__ src, bf16* __restrict__ dst,
                                bf16* __restrict__ xpT) {
    int idx = blockIdx.x * 256 + threadIdx.x;
    if (idx < CONVN) {
        int ci = idx & 511;
        int co = (idx >> 9) & 511;
        int it = idx >> 18;
        int tap = it % 3, ib = it / 3;
        dst[idx] = f2b(src[(((size_t)(ib * 512 + co)) * 512 + ci) * 3 + tap]);
    } else if (idx < CONVN + 32768) {
        int j = idx - CONVN;  // b*1024 + w*512 + ci
        int ci = j & 511;
        int w = (j >> 9) & 1;
        int b = j >> 10;
        xpT[((size_t)b * PADL + (w ? 513 : 0)) * 512 + ci] = f2b(0.0f);
    }
}

// ---- fused stats + build_x + rmsnorm (iter 0), coalesced via LDS tile ----
// grid: 32 b x 8 f-chunks of 64. LDS tile [t=256][f=64].
__global__ __launch_bounds__(256) void buildx_rms_kernel(
    const float* __restrict__ xe, const float* __restrict__ xm,
    const float* __restrict__ nw, float* __restrict__ means, float* __restrict__ stdev,
    bf16* __restrict__ XN) {
    __shared__ float L[256][65];
    __shared__ float red_s[4][64], red_q[4][64];
    __shared__ float stat_m[64], stat_i[64], scl[64];
    int blk = blockIdx.x;
    int b = blk >> 3, f0 = (blk & 7) * 64;
    int tid = threadIdx.x;
    int j = tid & 63, tq = tid >> 6;
    int f = f0 + j;
    float ps = 0.f, pq = 0.f;
    const float* xep = xe + (size_t)b * CT * CN + f;
    const float* xmp = xm + (size_t)b * CT * CM + (f - CN);
    #pragma unroll 4
    for (int tt = 0; tt < 64; tt++) {
        int t = tq * 64 + tt;
        float v = (f < CN) ? xep[(size_t)t * CN] : xmp[(size_t)t * CM];
        L[t][j] = v;
        ps += v;
        pq += v * v;
    }
    red_s[tq][j] = ps;
    red_q[tq][j] = pq;
    __syncthreads();
    if (tid < 64) {
        int ff = f0 + tid;
        float s = red_s[0][tid] + red_s[1][tid] + red_s[2][tid] + red_s[3][tid];
        float q = red_q[0][tid] + red_q[1][tid] + red_q[2][tid] + red_q[3][tid];
        float mean, isd, msq;
        if (ff < CN) {
            mean = s * (1.0f / 256.0f);
            float var = fmaxf(q * (1.0f / 256.0f) - mean * mean, 0.0f);
            float sd = sqrtf(var + 1e-5f);
            isd = 1.0f / sd;
            means[b * CN + ff] = mean;
            stdev[b * CN + ff] = sd;
            msq = var / (var + 1e-5f);  // mean of squares of normalized values
        } else {
            mean = 0.0f;
            isd = 1.0f;
            msq = q * (1.0f / 256.0f);
        }
        stat_m[tid] = mean;
        stat_i[tid] = isd;
        scl[tid] = rsqrtf(msq + 1e-5f);
    }
    __syncthreads();
    bf16* outp = XN + ((size_t)(b * 512 + f0)) * 256;
    int t = tid;
    float w = nw[t];
    #pragma unroll 4
    for (int fp = 0; fp < 64; fp++) {
        float val = (L[t][fp] - stat_m[fp]) * stat_i[fp];
        outp[(size_t)fp * 256 + t] = f2b(val * scl[fp] * w);
    }
}

// ---- MFMA GEMM (m97 structure). MODE 0: plain. MODE 1: [inp|D] split epilogue.
// MODE 3: [fc1|fc2|fc3] split epilogue.
template <int MODE>
__global__ __launch_bounds__(256) void mgemm_kernel(const bf16* __restrict__ A,
                                                    const bf16* __restrict__ Wt,
                                                    const float* __restrict__ b1,
                                                    const float* __restrict__ b2,
                                                    const float* __restrict__ b3,
                                                    bf16* __restrict__ o1,
                                                    bf16* __restrict__ o2,
                                                    int K, int Ncols) {
    __shared__ __align__(16) short As[128 * 32];
    __shared__ __align__(16) short Bs[128 * 32];
    const int tid = threadIdx.x;
    const int lane = tid & 63;
    const int wave = tid >> 6;
    const int m0 = blockIdx.x * 128, n0 = blockIdx.y * 128;

    const int srow0 = wave * 32;
    const int lrow = lane >> 2;
    const int lcol = (lane & 3) * 8;

    const bf16* aP0 = A + (size_t)(m0 + srow0 + lrow) * K + lcol;
    const bf16* aP1 = A + (size_t)(m0 + srow0 + 16 + lrow) * K + lcol;
    const bf16* bP0 = Wt + (size_t)(n0 + srow0 + lrow) * K + lcol;
    const bf16* bP1 = Wt + (size_t)(n0 + srow0 + 16 + lrow) * K + lcol;
    short* aL0 = &As[srow0 * 32];
    short* aL1 = &As[(srow0 + 16) * 32];
    short* bL0 = &Bs[srow0 * 32];
    short* bL1 = &Bs[(srow0 + 16) * 32];

    const int wm = (wave & 1) * 64, wn = (wave >> 1) * 64;
    const int fr = lane & 15, quad = lane >> 4;

    floatx4 acc[4][4];
    #pragma unroll
    for (int i = 0; i < 4; i++)
        #pragma unroll
        for (int j = 0; j < 4; j++) acc[i][j] = (floatx4){0.f, 0.f, 0.f, 0.f};

    for (int k0 = 0; k0 < K; k0 += 32) {
        gl_lds16(aP0 + k0, aL0);
        gl_lds16(aP1 + k0, aL1);
        gl_lds16(bP0 + k0, bL0);
        gl_lds16(bP1 + k0, bL1);
        __syncthreads();
        short8 af[4], bfv[4];
        #pragma unroll
        for (int i = 0; i < 4; i++) af[i] = *(const short8*)&As[(wm + i * 16 + fr) * 32 + quad * 8];
        #pragma unroll
        for (int j = 0; j < 4; j++) bfv[j] = *(const short8*)&Bs[(wn + j * 16 + fr) * 32 + quad * 8];
        #pragma unroll
        for (int i = 0; i < 4; i++)
            #pragma unroll
            for (int j = 0; j < 4; j++)
                acc[i][j] = __builtin_amdgcn_mfma_f32_16x16x32_bf16(af[i], bfv[j], acc[i][j], 0, 0, 0);
        __syncthreads();
    }

    if (MODE == 0) {
        #pragma unroll
        for (int j = 0; j < 4; j++) {
            int n = n0 + wn + j * 16 + fr;
            float bv = b1[n];
            #pragma unroll
            for (int i = 0; i < 4; i++) {
                int mb = m0 + wm + i * 16 + quad * 4;
                #pragma unroll
                for (int r = 0; r < 4; r++)
                    o1[(size_t)(mb + r) * Ncols + n] = f2b(acc[i][j][r] + bv);
            }
        }
    } else if (MODE == 1) {
        if (n0 + wn < 512) {
            int b = (m0 + wm) >> 9;
            #pragma unroll
            for (int j = 0; j < 4; j++) {
                int n = n0 + wn + j * 16 + fr;
                float bv = b1[n];
                bf16* dst = o1 + ((size_t)b * PADL + n + 1) * 512;
                #pragma unroll
                for (int i = 0; i < 4; i++) {
                    int ci = (m0 + wm + i * 16 + quad * 4) & 511;
                    short4v pk;
                    #pragma unroll
                    for (int r = 0; r < 4; r++) {
                        bf16 tb = f2b(acc[i][j][r] + bv);
                        pk[r] = __builtin_bit_cast(short, tb);
                    }
                    *(short4v*)(dst + ci) = pk;
                }
            }
        } else {
            #pragma unroll
            for (int j = 0; j < 4; j++) {
                int n = n0 + wn + j * 16 + fr;
                float bv = b2[n - 512];
                #pragma unroll
                for (int i = 0; i < 4; i++) {
                    int mb = m0 + wm + i * 16 + quad * 4;
                    #pragma unroll
                    for (int r = 0; r < 4; r++)
                        o2[(size_t)(mb + r) * 512 + (n - 512)] = f2b(silu_f(acc[i][j][r] + bv));
                }
            }
        }
    } else {  // MODE 3
        if (n0 + wn < 512) {
            #pragma unroll
            for (int j = 0; j < 4; j++) {
                int n = n0 + wn + j * 16 + fr;
                float bv = b1[n];
                #pragma unroll
                for (int i = 0; i < 4; i++) {
                    int mb = m0 + wm + i * 16 + quad * 4;
                    #pragma unroll
                    for (int r = 0; r < 4; r++)
                        o1[(size_t)(mb + r) * 512 + n] = f2b(acc[i][j][r] + bv);
                }
            }
        } else {
            #pragma unroll
            for (int j = 0; j < 4; j++) {
                int n = n0 + wn + j * 16 + fr;
                float bv = (n < 768) ? b2[n - 512] : b3[n - 768];
                #pragma unroll
                for (int i = 0; i < 4; i++) {
                    int mb = m0 + wm + i * 16 + quad * 4;
                    #pragma unroll
                    for (int r = 0; r < 4; r++)
                        o2[(size_t)(mb + r) * 512 + (n - 512)] = f2b(acc[i][j][r] + bv);
                }
            }
        }
    }
}

// ---- conv as implicit MFMA GEMM: 128co x 64l tile, 1024 blocks (4/CU), hoisted
// staging pointers, single B-stage shared across 3 taps, XCD swizzle ----
__global__ __launch_bounds__(256) void conv_mfma_kernel(const bf16* __restrict__ Wc,
                                                        const bf16* __restrict__ xpT,
                                                        const float* __restrict__ bias,
                                                        bf16* __restrict__ Out) {
    __shared__ __align__(16) short As[3 * 128 * 32];  // 24.6 KB
    __shared__ __align__(16) short Bs[80 * 32];       // 5 KB
    const int tid = threadIdx.x;
    const int lane = tid & 63;
    const int wave = tid >> 6;
    int bx = blockIdx.x;             // 1024 blocks
    int xcd = bx & 7, g = bx >> 3;   // g 0..127 per XCD
    int mt = g & 3;
    int nt = (g >> 2) & 7;
    int b = xcd * 4 + (g >> 5);
    const int m0 = mt * 128, n0 = nt * 64;
    const bf16* xb = xpT + (size_t)b * PADL * 512;

    const int lrow = lane >> 2;
    const int lcol = (lane & 3) * 8;
    const int wm = (wave & 1) * 64, wn = (wave >> 1) * 32;
    const int fr = lane & 15, quad = lane >> 4;

    // hoisted staging pointers: A 24 granules (6/wave), B 5 granules
    const bf16* aPtr[6];
    short* aLds[6];
    #pragma unroll
    for (int u = 0; u < 6; u++) {
        int ga = wave + 4 * u;
        int tap = ga >> 3, rg = ga & 7;
        aPtr[u] = Wc + (size_t)tap * 262144 + (size_t)(m0 + rg * 16 + lrow) * 512 + lcol;
        aLds[u] = &As[ga * 512];
    }
    const bf16* bPtr0 = xb + (size_t)(n0 + wave * 16 + lrow) * 512 + lcol;
    short* bLds0 = &Bs[wave * 16 * 32];
    const bf16* bPtr1 = xb + (size_t)(n0 + 64 + lrow) * 512 + lcol;
    short* bLds1 = &Bs[64 * 32];

    floatx4 acc[4][2];
    #pragma unroll
    for (int i = 0; i < 4; i++)
        #pragma unroll
        for (int j = 0; j < 2; j++) acc[i][j] = (floatx4){0.f, 0.f, 0.f, 0.f};

    for (int k0 = 0; k0 < 512; k0 += 32) {
        #pragma unroll
        for (int u = 0; u < 6; u++) {
            gl_lds16(aPtr[u], aLds[u]);
            aPtr[u] += 32;
        }
        gl_lds16(bPtr0, bLds0);
        bPtr0 += 32;
        if (wave == 0) gl_lds16(bPtr1, bLds1);
        bPtr1 += 32;
        __syncthreads();
        #pragma unroll
        for (int tap = 0; tap < 3; tap++) {
            short8 af[4], bfv[2];
            #pragma unroll
            for (int i = 0; i < 4; i++)
                af[i] = *(const short8*)&As[tap * 4096 + (wm + i * 16 + fr) * 32 + quad * 8];
            #pragma unroll
            for (int j = 0; j < 2; j++)
                bfv[j] = *(const short8*)&Bs[(wn + j * 16 + fr + tap) * 32 + quad * 8];
            #pragma unroll
            for (int i = 0; i < 4; i++)
                #pragma unroll
                for (int j = 0; j < 2; j++)
                    acc[i][j] = __builtin_amdgcn_mfma_f32_16x16x32_bf16(af[i], bfv[j], acc[i][j], 0, 0, 0);
        }
        __syncthreads();
    }
    bf16* ob = Out + (size_t)b * CF * CT2;
    #pragma unroll
    for (int i = 0; i < 4; i++) {
        int mb = m0 + wm + i * 16 + quad * 4;
        #pragma unroll
        for (int r = 0; r < 4; r++) {
            float bv = bias[mb + r];
            #pragma unroll
            for (int j = 0; j < 2; j++) {
                int n = n0 + wn + j * 16 + fr;
                ob[(size_t)(mb + r) * CT2 + n] = f2b(silu_f(acc[i][j][r] + bv));
            }
        }
    }
}

// ---- fused cb + s6 gate ----
__global__ __launch_bounds__(256) void gate_kernel(bf16* __restrict__ P,
                                                   const bf16* __restrict__ xco,
                                                   const bf16* __restrict__ E,
                                                   const bf16* __restrict__ xres) {
    __shared__ float red[4];
    int row = blockIdx.x;
    int t = threadIdx.x;
    size_t base = (size_t)row * 512;
    float s = b2f(E[base + t]) * b2f(E[base + 256 + t]);
    #pragma unroll
    for (int o = 32; o > 0; o >>= 1) s += __shfl_down(s, o);
    if ((t & 63) == 0) red[t >> 6] = s;
    __syncthreads();
    float cb = red[0] + red[1] + red[2] + red[3];
    #pragma unroll
    for (int h = 0; h < 2; h++) {
        size_t idx = base + t + h * 256;
        float delta = softplus_f(b2f(P[idx]));
        float xssm = delta * b2f(xco[idx]) * cb;
        P[idx] = f2b(silu_f(xssm) * b2f(xres[idx]));
    }
}

// ---- out-GEMM (K=512, N=256 full width) with FUSED rmsnorm epilogue ----
__global__ __launch_bounds__(256) void gemm_rms_kernel(const bf16* __restrict__ A,
                                                       const bf16* __restrict__ Wt,
                                                       const float* __restrict__ bias,
                                                       const float* __restrict__ nw,
                                                       bf16* __restrict__ Xo,
                                                       bf16* __restrict__ XNo) {
    __shared__ __align__(16) short As[64 * 32];
    __shared__ __align__(16) short Bs[256 * 32];
    __shared__ float red[4][64];
    __shared__ float scl[64];
    const int tid = threadIdx.x;
    const int lane = tid & 63;
    const int wave = tid >> 6;
    const int m0 = blockIdx.x * 64;

    const int lrow = lane >> 2;
    const int lcol = (lane & 3) * 8;
    const bf16* aP = A + (size_t)(m0 + wave * 16 + lrow) * 512 + lcol;
    short* aL = &As[wave * 16 * 32];
    const bf16* bP[4];
    short* bL[4];
    #pragma unroll
    for (int g = 0; g < 4; g++) {
        int r0 = (wave * 4 + g) * 16;
        bP[g] = Wt + (size_t)(r0 + lrow) * 512 + lcol;
        bL[g] = &Bs[r0 * 32];
    }
    const int wn = wave * 64;
    const int fr = lane & 15, quad = lane >> 4;

    floatx4 acc[4][4];
    #pragma unroll
    for (int i = 0; i < 4; i++)
        #pragma unroll
        for (int j = 0; j < 4; j++) acc[i][j] = (floatx4){0.f, 0.f, 0.f, 0.f};

    for (int k0 = 0; k0 < 512; k0 += 32) {
        gl_lds16(aP + k0, aL);
        #pragma unroll
        for (int g = 0; g < 4; g++) gl_lds16(bP[g] + k0, bL[g]);
        __syncthreads();
        short8 af[4], bfv[4];
        #pragma unroll
        for (int i = 0; i < 4; i++) af[i] = *(const short8*)&As[(i * 16 + fr) * 32 + quad * 8];
        #pragma unroll
        for (int j = 0; j < 4; j++) bfv[j] = *(const short8*)&Bs[(wn + j * 16 + fr) * 32 + quad * 8];
        #pragma unroll
        for (int i = 0; i < 4; i++)
            #pragma unroll
            for (int j = 0; j < 4; j++)
                acc[i][j] = __builtin_amdgcn_mfma_f32_16x16x32_bf16(af[i], bfv[j], acc[i][j], 0, 0, 0);
        __syncthreads();
    }
    #pragma unroll
    for (int j = 0; j < 4; j++) {
        float bv = bias[wn + j * 16 + fr];
        #pragma unroll
        for (int i = 0; i < 4; i++)
            #pragma unroll
            for (int r = 0; r < 4; r++) acc[i][j][r] += bv;
    }
    #pragma unroll
    for (int i = 0; i < 4; i++) {
        #pragma unroll
        for (int r = 0; r < 4; r++) {
            float s = 0.f;
            #pragma unroll
            for (int j = 0; j < 4; j++) s += acc[i][j][r] * acc[i][j][r];
            #pragma unroll
            for (int o = 8; o > 0; o >>= 1) s += __shfl_xor(s, o);
            if (fr == 0) red[wave][i * 16 + quad * 4 + r] = s;
        }
    }
    __syncthreads();
    if (tid < 64) {
        float tot = red[0][tid] + red[1][tid] + red[2][tid] + red[3][tid];
        scl[tid] = rsqrtf(tot * (1.0f / CT) + 1e-5f);
    }
    __syncthreads();
    #pragma unroll
    for (int j = 0; j < 4; j++) {
        int n = wn + j * 16 + fr;
        float w = nw[n];
        #pragma unroll
        for (int i = 0; i < 4; i++) {
            int rl = i * 16 + quad * 4;
            #pragma unroll
            for (int r = 0; r < 4; r++) {
                float v = acc[i][j][r];
                Xo[(size_t)(m0 + rl + r) * CT + n] = f2b(v);
                XNo[(size_t)(m0 + rl + r) * CT + n] = f2b(v * scl[rl + r] * w);
            }
        }
    }
}

// ---- proj GEMM (K=256, N=256) with fused de-norm + transpose to fp32 out ----
__global__ __launch_bounds__(256) void proj_out_kernel(const bf16* __restrict__ A,
                                                       const bf16* __restrict__ Wt,
                                                       const float* __restrict__ bias,
                                                       const float* __restrict__ means,
                                                       const float* __restrict__ stdev,
                                                       float* __restrict__ out) {
    __shared__ __align__(16) short As[128 * 32];
    __shared__ __align__(16) short Bs[128 * 32];
    const int tid = threadIdx.x;
    const int lane = tid & 63;
    const int wave = tid >> 6;
    const int m0 = blockIdx.x * 128, n0 = blockIdx.y * 128;

    const int srow0 = wave * 32;
    const int lrow = lane >> 2;
    const int lcol = (lane & 3) * 8;
    const bf16* aP0 = A + (size_t)(m0 + srow0 + lrow) * 256 + lcol;
    const bf16* aP1 = A + (size_t)(m0 + srow0 + 16 + lrow) * 256 + lcol;
    const bf16* bP0 = Wt + (size_t)(n0 + srow0 + lrow) * 256 + lcol;
    const bf16* bP1 = Wt + (size_t)(n0 + srow0 + 16 + lrow) * 256 + lcol;
    short* aL0 = &As[srow0 * 32];
    short* aL1 = &As[(srow0 + 16) * 32];
    short* bL0 = &Bs[srow0 * 32];
    short* bL1 = &Bs[(srow0 + 16) * 32];

    const int wm = (wave & 1) * 64, wn = (wave >> 1) * 64;
    const int fr = lane & 15, quad = lane >> 4;

    floatx4 acc[4][4];
    #pragma unroll
    for (int i = 0; i < 4; i++)
        #pragma unroll
        for (int j = 0; j < 4; j++) acc[i][j] = (floatx4){0.f, 0.f, 0.f, 0.f};

    for (int k0 = 0; k0 < 256; k0 += 32) {
        gl_lds16(aP0 + k0, aL0);
        gl_lds16(aP1 + k0, aL1);
        gl_lds16(bP0 + k0, bL0);
        gl_lds16(bP1 + k0, bL1);
        __syncthreads();
        short8 af[4], bfv[4];
        #pragma unroll
        for (int i = 0; i < 4; i++) af[i] = *(const short8*)&As[(wm + i * 16 + fr) * 32 + quad * 8];
        #pragma unroll
        for (int j = 0; j < 4; j++) bfv[j] = *(const short8*)&Bs[(wn + j * 16 + fr) * 32 + quad * 8];
        #pragma unroll
        for (int i = 0; i < 4; i++)
            #pragma unroll
            for (int j = 0; j < 4; j++)
                acc[i][j] = __builtin_amdgcn_mfma_f32_16x16x32_bf16(af[i], bfv[j], acc[i][j], 0, 0, 0);
        __syncthreads();
    }
    #pragma unroll
    for (int j = 0; j < 4; j++) {
        int t = n0 + wn + j * 16 + fr;
        float bv = bias[t];
        #pragma unroll
        for (int i = 0; i < 4; i++) {
            int mb = m0 + wm + i * 16 + quad * 4;
            int b = mb >> 9;
            int nv = mb & 511;
            if (nv < CN) {
                floatx4 o;
                #pragma unroll
                for (int r = 0; r < 4; r++) {
                    int sn = b * CN + nv + r;
                    o[r] = (acc[i][j][r] + bv) * stdev[sn] + means[sn];
                }
                *(floatx4*)(out + ((size_t)(b * CT + t)) * CN + nv) = o;
            }
        }
    }
}

extern "C" void kernel_launch(void* const* d_in, const int* in_sizes, int n_in,
                              void* d_out, int out_size, void* d_ws, size_t ws_size,
                              hipStream_t stream) {
    const float* x_enc  = (const float*)d_in[0];
    const float* x_mark = (const float*)d_in[1];
    const float* norm_w = (const float*)d_in[4];
    const float* inp_W  = (const float*)d_in[5];
    const float* inp_b  = (const float*)d_in[6];
    const float* conv_W = (const float*)d_in[7];
    const float* conv_b = (const float*)d_in[8];
    const float* convlin_W = (const float*)d_in[9];
    const float* convlin_b = (const float*)d_in[10];
    const float* fc1_W = (const float*)d_in[11];
    const float* fc1_b = (const float*)d_in[12];
    const float* fc2_W = (const float*)d_in[13];
    const float* fc2_b = (const float*)d_in[14];
    const float* fc3_W = (const float*)d_in[15];
    const float* fc3_b = (const float*)d_in[16];
    const float* D_W   = (const float*)d_in[17];
    const float* D_b   = (const float*)d_in[18];
    const float* out_W = (const float*)d_in[19];
    const float* out_b = (const float*)d_in[20];
    const float* proj_W = (const float*)d_in[21];
    const float* proj_b = (const float*)d_in[22];

    // ---- workspace layout ----
    char* ws = (char*)d_ws;
    float* MEANS = (float*)(ws);
    float* STDEV = (float*)(ws + 65536);
    bf16* wt = (bf16*)(ws + 131072);
    bf16* wt_g1      = wt;                   // 3 x [1024][256]  (inp^T | D^T)
    bf16* wt_g3      = wt + 786432;          // 3 x [1024][512]  (fc1^T | fc2^T | fc3^T)
    bf16* wt_convlin = wt + 2359296;         // 3 x [512][512]
    bf16* wt_out     = wt + 3145728;         // 3 x [256][512]
    bf16* wt_proj    = wt + 3538944;         // [256][256]
    bf16* wt_conv    = wt + 3604480;         // 3 x [3][512][512]
    bf16* xpT = (bf16*)(ws + 12058624);      // [32][528][512]
    const size_t POOLB = 16777216;
    const size_t HALF = 16384 * 256;
    bf16* pool[3] = {
        (bf16*)(ws + 29360128),
        (bf16*)(ws + 29360128 + POOLB),
        (bf16*)(ws + 29360128 + 2 * POOLB),
    };
    bf16* E = (bf16*)(ws + 29360128 + 3 * POOLB);  // [16384][512]: Bmat|Cmat
    float* out = (float*)d_out;

    // ---- prepack ----
    P8 p;
    p.s[0] = inp_W;  p.d[0] = wt_g1;
    p.s[1] = D_W;    p.d[1] = wt_g1 + 131072;
    p.s[2] = fc1_W;  p.d[2] = wt_g3;
    p.s[3] = fc2_W;  p.d[3] = wt_g3 + 262144;
    p.s[4] = fc3_W;  p.d[4] = wt_g3 + 393216;
    p.s[5] = convlin_W; p.d[5] = wt_convlin;
    p.s[6] = out_W;  p.d[6] = wt_out;
    p.s[7] = proj_W; p.d[7] = wt_proj;
    prepack_all_kernel<<<3520, 256, 0, stream>>>(p);
    convpack_kernel<<<(CONVN + 32768 + 255) / 256, 256, 0, stream>>>(conv_W, wt_conv, xpT);

    // ---- fused stats + build + rmsnorm(iter0): xn -> pool[0].hi ----
    buildx_rms_kernel<<<256, 256, 0, stream>>>(x_enc, x_mark, norm_w, MEANS, STDEV,
                                               pool[0] + HALF);

    for (int i = 0; i < 3; i++) {
        bf16* A  = pool[i % 3];         // xn(hi) -> xc -> P/gate
        bf16* Bp = pool[(i + 1) % 3];   // xco -> x_next(lo)+xn_next(hi)
        bf16* Cp = pool[(i + 2) % 3];   // xres
        bf16* XN = A + HALF;

        // [xp|xres] = xn @ [inp|D] + b : xp -> xpT (transposed), xres -> Cp
        mgemm_kernel<1><<<dim3(128, 8), 256, 0, stream>>>(
            XN, wt_g1 + (size_t)i * 262144, inp_b + i * CT2, D_b + i * CT2, nullptr,
            xpT, Cp, 256, 1024);
        // xc = silu(conv(xp)) -> A
        conv_mfma_kernel<<<1024, 256, 0, stream>>>(wt_conv + (size_t)i * 786432, xpT,
                                                   conv_b + i * CF, A);
        // xco = xc @ convlin + b -> Bp
        mgemm_kernel<0><<<dim3(128, 4), 256, 0, stream>>>(
            A, wt_convlin + (size_t)i * 262144, convlin_b + i * CT2, nullptr, nullptr,
            Bp, nullptr, 512, 512);
        // [P|Bmat|Cmat] = xco @ [fc1|fc2|fc3] + b : P -> A, Bmat|Cmat -> E
        mgemm_kernel<3><<<dim3(128, 8), 256, 0, stream>>>(
            Bp, wt_g3 + (size_t)i * 524288, fc1_b + i * CT2, fc2_b + i * CT, fc3_b + i * CT,
            A, E, 512, 1024);
        // gate in-place on A
        gate_kernel<<<MROWS, 256, 0, stream>>>(A, Bp, E, Cp);
        // x_next = gate @ out_W + b -> Bp.lo ; xn_next = rmsnorm(x_next) -> Bp.hi
        gemm_rms_kernel<<<256, 256, 0, stream>>>(
            A, wt_out + (size_t)i * 131072, out_b + i * CT,
            norm_w + ((i + 1) % 3) * CT, Bp, Bp + HALF);
    }

    // dec = x @ proj_W + b, de-normalized + transposed straight to fp32 out
    proj_out_kernel<<<dim3(128, 2), 256, 0, stream>>>(
        pool[0], wt_proj, proj_b, MEANS, STDEV, out);
}

// Round 8
// 656.235 us; speedup vs baseline: 1.0225x; 1.0225x over previous
//
#include <hip/hip_runtime.h>
#include <hip/hip_bf16.h>
#include <math.h>

typedef __hip_bfloat16 bf16;
typedef short short8 __attribute__((ext_vector_type(8)));
typedef short short4v __attribute__((ext_vector_type(4)));
typedef float floatx4 __attribute__((ext_vector_type(4)));

constexpr int CB_ = 32;
constexpr int CT = 256;
constexpr int CF = 512;
constexpr int CN = 508;
constexpr int CM = 4;
constexpr int CT2 = 512;
constexpr int MROWS = CB_ * CF;  // 16384
constexpr int PADL = 528;       // xpT rows/batch: 0 pad, 1..512 live, 513 pad, rest slack

__device__ __forceinline__ float b2f(bf16 v) { return __bfloat162float(v); }
__device__ __forceinline__ bf16 f2b(float v) { return __float2bfloat16(v); }
__device__ __forceinline__ float s2f(short s) {
    unsigned u = ((unsigned)(unsigned short)s) << 16;
    return __builtin_bit_cast(float, u);
}
__device__ __forceinline__ short f2s(float v) {
    bf16 t = __float2bfloat16(v);
    return __builtin_bit_cast(short, t);
}
__device__ __forceinline__ float silu_f(float x) { return x / (1.0f + expf(-x)); }
__device__ __forceinline__ float softplus_f(float x) {
    return fmaxf(x, 0.0f) + log1pf(expf(-fabsf(x)));
}

__device__ __forceinline__ void gl_lds16(const bf16* g, short* l) {
    __builtin_amdgcn_global_load_lds(
        (const __attribute__((address_space(1))) unsigned int*)(g),
        (__attribute__((address_space(3))) unsigned int*)(l), 16, 0, 0);
}

// ---- merged weight prepack: 8 matrices, W(KxN fp32) -> Wt(NxK bf16).
// fc2/fc3 are INTERLEAVED into one [512][512] region: dst row = 2c (fc2) / 2c+1 (fc3).
struct P8 { const float* s[8]; bf16* d[8]; };
__global__ __launch_bounds__(256) void prepack_all_kernel(P8 p) {
    const int Ks[8]   = {256, 256, 512, 512, 512, 512, 512, 256};
    const int Ns[8]   = {512, 512, 512, 256, 256, 512, 256, 256};
    const int zs[8]   = {3, 3, 3, 3, 3, 3, 3, 1};
    const int dstr[8] = {262144, 262144, 524288, 524288, 524288, 262144, 131072, 65536};
    const int rml[8]  = {1, 1, 1, 2, 2, 1, 1, 1};   // dst row multiplier
    const int rad[8]  = {0, 0, 0, 0, 1, 0, 0, 0};   // dst row offset
    int bid = blockIdx.x;
    int m = 0, acc = 0;
    for (m = 0; m < 8; m++) {
        int c = (Ns[m] >> 5) * (Ks[m] >> 5) * zs[m];
        if (bid < acc + c) break;
        acc += c;
    }
    int lid = bid - acc;
    int K = Ks[m], N = Ns[m];
    int tx = N >> 5, ty = K >> 5;
    int z = lid / (tx * ty), rem = lid % (tx * ty);
    int k0 = (rem / tx) * 32, n0 = (rem % tx) * 32;
    const float* s = p.s[m] + (size_t)z * K * N;
    bf16* d = p.d[m] + (size_t)z * dstr[m];
    int mul = rml[m], add = rad[m];
    __shared__ float Ts[32][33];
    for (int e = threadIdx.x; e < 1024; e += 256) {
        int r = e >> 5, c = e & 31;
        Ts[r][c] = s[(size_t)(k0 + r) * N + n0 + c];
    }
    __syncthreads();
    for (int e = threadIdx.x; e < 1024; e += 256) {
        int r = e >> 5, c = e & 31;
        d[(size_t)((n0 + r) * mul + add) * K + k0 + c] = f2b(Ts[c][r]);
    }
}

// ---- conv weight pack + xpT pad-row zero + CBv zero (merged) ----
constexpr int CONVN = 3 * 3 * 512 * 512;  // 2359296
__global__ void convpack_kernel(const float* __restrict__ src, bf16* __restrict__ dst,
                                bf16* __restrict__ xpT, float* __restrict__ CBv) {
    int idx = blockIdx.x * 256 + threadIdx.x;
    if (idx < CONVN) {
        int ci = idx & 511;
        int co = (idx >> 9) & 511;
        int it = idx >> 18;
        int tap = it % 3, ib = it / 3;
        dst[idx] = f2b(src[(((size_t)(ib * 512 + co)) * 512 + ci) * 3 + tap]);
    } else if (idx < CONVN + 32768) {
        int j = idx - CONVN;
        int ci = j & 511;
        int w = (j >> 9) & 1;
        int b = j >> 10;
        xpT[((size_t)b * PADL + (w ? 513 : 0)) * 512 + ci] = f2b(0.0f);
    } else if (idx < CONVN + 32768 + MROWS) {
        CBv[idx - CONVN - 32768] = 0.0f;
    }
}

// ---- fused stats + build_x + rmsnorm (iter 0), coalesced via LDS tile ----
__global__ __launch_bounds__(256) void buildx_rms_kernel(
    const float* __restrict__ xe, const float* __restrict__ xm,
    const float* __restrict__ nw, float* __restrict__ means, float* __restrict__ stdev,
    bf16* __restrict__ XN) {
    __shared__ float L[256][65];
    __shared__ float red_s[4][64], red_q[4][64];
    __shared__ float stat_m[64], stat_i[64], scl[64];
    int blk = blockIdx.x;
    int b = blk >> 3, f0 = (blk & 7) * 64;
    int tid = threadIdx.x;
    int j = tid & 63, tq = tid >> 6;
    int f = f0 + j;
    float ps = 0.f, pq = 0.f;
    const float* xep = xe + (size_t)b * CT * CN + f;
    const float* xmp = xm + (size_t)b * CT * CM + (f - CN);
    #pragma unroll 4
    for (int tt = 0; tt < 64; tt++) {
        int t = tq * 64 + tt;
        float v = (f < CN) ? xep[(size_t)t * CN] : xmp[(size_t)t * CM];
        L[t][j] = v;
        ps += v;
        pq += v * v;
    }
    red_s[tq][j] = ps;
    red_q[tq][j] = pq;
    __syncthreads();
    if (tid < 64) {
        int ff = f0 + tid;
        float s = red_s[0][tid] + red_s[1][tid] + red_s[2][tid] + red_s[3][tid];
        float q = red_q[0][tid] + red_q[1][tid] + red_q[2][tid] + red_q[3][tid];
        float mean, isd, msq;
        if (ff < CN) {
            mean = s * (1.0f / 256.0f);
            float var = fmaxf(q * (1.0f / 256.0f) - mean * mean, 0.0f);
            float sd = sqrtf(var + 1e-5f);
            isd = 1.0f / sd;
            means[b * CN + ff] = mean;
            stdev[b * CN + ff] = sd;
            msq = var / (var + 1e-5f);
        } else {
            mean = 0.0f;
            isd = 1.0f;
            msq = q * (1.0f / 256.0f);
        }
        stat_m[tid] = mean;
        stat_i[tid] = isd;
        scl[tid] = rsqrtf(msq + 1e-5f);
    }
    __syncthreads();
    bf16* outp = XN + ((size_t)(b * 512 + f0)) * 256;
    int t = tid;
    float w = nw[t];
    #pragma unroll 4
    for (int fp = 0; fp < 64; fp++) {
        float val = (L[t][fp] - stat_m[fp]) * stat_i[fp];
        outp[(size_t)fp * 256 + t] = f2b(val * scl[fp] * w);
    }
}

// ---- MFMA GEMM (m97 structure). MODE 0: plain. MODE 1: [inp|D] split epilogue.
// MODE 3: [fc1 | fc2⊕fc3-interleaved]: n<512 -> P stores; n>=512 -> cb atomics only.
template <int MODE>
__global__ __launch_bounds__(256) void mgemm_kernel(const bf16* __restrict__ A,
                                                    const bf16* __restrict__ Wt,
                                                    const float* __restrict__ b1,
                                                    const float* __restrict__ b2,
                                                    const float* __restrict__ b3,
                                                    bf16* __restrict__ o1,
                                                    bf16* __restrict__ o2,
                                                    float* __restrict__ CBv,
                                                    int K, int Ncols) {
    __shared__ __align__(16) short As[128 * 32];
    __shared__ __align__(16) short Bs[128 * 32];
    const int tid = threadIdx.x;
    const int lane = tid & 63;
    const int wave = tid >> 6;
    const int m0 = blockIdx.x * 128, n0 = blockIdx.y * 128;

    const int srow0 = wave * 32;
    const int lrow = lane >> 2;
    const int lcol = (lane & 3) * 8;

    const bf16* aP0 = A + (size_t)(m0 + srow0 + lrow) * K + lcol;
    const bf16* aP1 = A + (size_t)(m0 + srow0 + 16 + lrow) * K + lcol;
    const bf16* bP0 = Wt + (size_t)(n0 + srow0 + lrow) * K + lcol;
    const bf16* bP1 = Wt + (size_t)(n0 + srow0 + 16 + lrow) * K + lcol;
    short* aL0 = &As[srow0 * 32];
    short* aL1 = &As[(srow0 + 16) * 32];
    short* bL0 = &Bs[srow0 * 32];
    short* bL1 = &Bs[(srow0 + 16) * 32];

    const int wm = (wave & 1) * 64, wn = (wave >> 1) * 64;
    const int fr = lane & 15, quad = lane >> 4;

    floatx4 acc[4][4];
    #pragma unroll
    for (int i = 0; i < 4; i++)
        #pragma unroll
        for (int j = 0; j < 4; j++) acc[i][j] = (floatx4){0.f, 0.f, 0.f, 0.f};

    for (int k0 = 0; k0 < K; k0 += 32) {
        gl_lds16(aP0 + k0, aL0);
        gl_lds16(aP1 + k0, aL1);
        gl_lds16(bP0 + k0, bL0);
        gl_lds16(bP1 + k0, bL1);
        __syncthreads();
        short8 af[4], bfv[4];
        #pragma unroll
        for (int i = 0; i < 4; i++) af[i] = *(const short8*)&As[(wm + i * 16 + fr) * 32 + quad * 8];
        #pragma unroll
        for (int j = 0; j < 4; j++) bfv[j] = *(const short8*)&Bs[(wn + j * 16 + fr) * 32 + quad * 8];
        #pragma unroll
        for (int i = 0; i < 4; i++)
            #pragma unroll
            for (int j = 0; j < 4; j++)
                acc[i][j] = __builtin_amdgcn_mfma_f32_16x16x32_bf16(af[i], bfv[j], acc[i][j], 0, 0, 0);
        __syncthreads();
    }

    if (MODE == 0) {
        #pragma unroll
        for (int j = 0; j < 4; j++) {
            int n = n0 + wn + j * 16 + fr;
            float bv = b1[n];
            #pragma unroll
            for (int i = 0; i < 4; i++) {
                int mb = m0 + wm + i * 16 + quad * 4;
                #pragma unroll
                for (int r = 0; r < 4; r++)
                    o1[(size_t)(mb + r) * Ncols + n] = f2b(acc[i][j][r] + bv);
            }
        }
    } else if (MODE == 1) {
        if (n0 + wn < 512) {
            int b = (m0 + wm) >> 9;
            #pragma unroll
            for (int j = 0; j < 4; j++) {
                int n = n0 + wn + j * 16 + fr;
                float bv = b1[n];
                bf16* dst = o1 + ((size_t)b * PADL + n + 1) * 512;
                #pragma unroll
                for (int i = 0; i < 4; i++) {
                    int ci = (m0 + wm + i * 16 + quad * 4) & 511;
                    short4v pk;
                    #pragma unroll
                    for (int r = 0; r < 4; r++) pk[r] = f2s(acc[i][j][r] + bv);
                    *(short4v*)(dst + ci) = pk;
                }
            }
        } else {
            #pragma unroll
            for (int j = 0; j < 4; j++) {
                int n = n0 + wn + j * 16 + fr;
                float bv = b2[n - 512];
                #pragma unroll
                for (int i = 0; i < 4; i++) {
                    int mb = m0 + wm + i * 16 + quad * 4;
                    #pragma unroll
                    for (int r = 0; r < 4; r++)
                        o2[(size_t)(mb + r) * 512 + (n - 512)] = f2b(silu_f(acc[i][j][r] + bv));
                }
            }
        }
    } else {  // MODE 3
        if (n0 + wn < 512) {
            #pragma unroll
            for (int j = 0; j < 4; j++) {
                int n = n0 + wn + j * 16 + fr;
                float bv = b1[n];
                #pragma unroll
                for (int i = 0; i < 4; i++) {
                    int mb = m0 + wm + i * 16 + quad * 4;
                    #pragma unroll
                    for (int r = 0; r < 4; r++)
                        o1[(size_t)(mb + r) * 512 + n] = f2b(acc[i][j][r] + bv);
                }
            }
        } else {
            // interleaved fc2/fc3: col nn=2c -> Bmat_c, nn=2c+1 -> Cmat_c.
            // partial cb[row] += sum_c (Bmat_c+b2[c])*(Cmat_c+b3[c]) via shfl_xor(1).
            int nnb = (n0 - 512) + wn;
            float bv[4];
            #pragma unroll
            for (int j = 0; j < 4; j++) {
                int nn = nnb + j * 16 + fr;
                int c = nn >> 1;
                bv[j] = (fr & 1) ? b3[c] : b2[c];
            }
            #pragma unroll
            for (int i = 0; i < 4; i++) {
                #pragma unroll
                for (int r = 0; r < 4; r++) {
                    float s = 0.f;
                    #pragma unroll
                    for (int j = 0; j < 4; j++) {
                        float v = acc[i][j][r] + bv[j];
                        s += v * __shfl_xor(v, 1);
                    }
                    s += __shfl_xor(s, 2);
                    s += __shfl_xor(s, 4);
                    s += __shfl_xor(s, 8);
                    if (fr == 0)
                        atomicAdd(&CBv[m0 + wm + i * 16 + quad * 4 + r], s * 0.5f);
                }
            }
        }
    }
}

// ---- conv as implicit MFMA GEMM (R6 version): 128x128 tile, 512 blocks,
// single B-stage for all 3 taps, XCD swizzle ----
__global__ __launch_bounds__(256) void conv_mfma_kernel(const bf16* __restrict__ Wc,
                                                        const bf16* __restrict__ xpT,
                                                        const float* __restrict__ bias,
                                                        bf16* __restrict__ Out) {
    __shared__ __align__(16) short As[3 * 128 * 32];
    __shared__ __align__(16) short Bs[144 * 32];
    const int tid = threadIdx.x;
    const int lane = tid & 63;
    const int wave = tid >> 6;
    int bx = blockIdx.x;
    int xcd = bx & 7, g = bx >> 3;
    int mt = g & 3;
    int id = xcd * 16 + (g >> 2);
    int nt = id & 3, b = id >> 2;
    const int m0 = mt * 128, n0 = nt * 128;
    const bf16* xb = xpT + (size_t)b * PADL * 512;

    const int lrow = lane >> 2;
    const int lcol = (lane & 3) * 8;
    const int wm = (wave & 1) * 64, wn = (wave >> 1) * 64;
    const int fr = lane & 15, quad = lane >> 4;

    floatx4 acc[4][4];
    #pragma unroll
    for (int i = 0; i < 4; i++)
        #pragma unroll
        for (int j = 0; j < 4; j++) acc[i][j] = (floatx4){0.f, 0.f, 0.f, 0.f};

    for (int k0 = 0; k0 < 512; k0 += 32) {
        for (int ga = wave; ga < 24; ga += 4) {
            int tap = ga >> 3, rg = ga & 7;
            gl_lds16(Wc + (size_t)tap * 262144 + (size_t)(m0 + rg * 16 + lrow) * 512 + k0 + lcol,
                     &As[ga * 512]);
        }
        for (int gb = wave; gb < 9; gb += 4) {
            gl_lds16(xb + (size_t)(n0 + gb * 16 + lrow) * 512 + k0 + lcol, &Bs[gb * 512]);
        }
        __syncthreads();
        #pragma unroll
        for (int tap = 0; tap < 3; tap++) {
            short8 af[4], bfv[4];
            #pragma unroll
            for (int i = 0; i < 4; i++)
                af[i] = *(const short8*)&As[tap * 4096 + (wm + i * 16 + fr) * 32 + quad * 8];
            #pragma unroll
            for (int j = 0; j < 4; j++)
                bfv[j] = *(const short8*)&Bs[(wn + j * 16 + fr + tap) * 32 + quad * 8];
            #pragma unroll
            for (int i = 0; i < 4; i++)
                #pragma unroll
                for (int j = 0; j < 4; j++)
                    acc[i][j] = __builtin_amdgcn_mfma_f32_16x16x32_bf16(af[i], bfv[j], acc[i][j], 0, 0, 0);
        }
        __syncthreads();
    }
    bf16* ob = Out + (size_t)b * CF * CT2;
    #pragma unroll
    for (int i = 0; i < 4; i++) {
        int mb = m0 + wm + i * 16 + quad * 4;
        #pragma unroll
        for (int r = 0; r < 4; r++) {
            float bv = bias[mb + r];
            #pragma unroll
            for (int j = 0; j < 4; j++) {
                int n = n0 + wn + j * 16 + fr;
                ob[(size_t)(mb + r) * CT2 + n] = f2b(silu_f(acc[i][j][r] + bv));
            }
        }
    }
}

// ---- out-GEMM (K=512, N=256 full width) with FUSED s6-gate on A-staging and
// FUSED rmsnorm epilogue. A := silu(softplus(P)*xco*cb)*xres computed in-register.
// Also zeroes CBv for the next iteration.
__global__ __launch_bounds__(256) void gemm_rms_kernel(const bf16* __restrict__ P,
                                                       const bf16* __restrict__ Xco,
                                                       const bf16* __restrict__ Xres,
                                                       float* __restrict__ CBv,
                                                       const bf16* __restrict__ Wt,
                                                       const float* __restrict__ bias,
                                                       const float* __restrict__ nw,
                                                       bf16* __restrict__ Xo,
                                                       bf16* __restrict__ XNo) {
    __shared__ __align__(16) short As[64 * 32];
    __shared__ __align__(16) short Bs[256 * 32];
    __shared__ float red[4][64];
    __shared__ float scl[64];
    const int tid = threadIdx.x;
    const int lane = tid & 63;
    const int wave = tid >> 6;
    const int m0 = blockIdx.x * 64;

    const int lrow = lane >> 2;
    const int lcol = (lane & 3) * 8;
    const int arow = m0 + wave * 16 + lrow;
    const bf16* pP = P + (size_t)arow * 512 + lcol;
    const bf16* pC = Xco + (size_t)arow * 512 + lcol;
    const bf16* pR = Xres + (size_t)arow * 512 + lcol;
    short* aDst = &As[(wave * 16 + lrow) * 32 + lcol];
    float cbv = CBv[arow];
    if ((lane & 3) == 0) CBv[arow] = 0.0f;  // wave-lockstep: all reads precede this write

    const bf16* bP[4];
    short* bL[4];
    #pragma unroll
    for (int g = 0; g < 4; g++) {
        int r0 = (wave * 4 + g) * 16;
        bP[g] = Wt + (size_t)(r0 + lrow) * 512 + lcol;
        bL[g] = &Bs[r0 * 32];
    }
    const int wn = wave * 64;
    const int fr = lane & 15, quad = lane >> 4;

    floatx4 acc[4][4];
    #pragma unroll
    for (int i = 0; i < 4; i++)
        #pragma unroll
        for (int j = 0; j < 4; j++) acc[i][j] = (floatx4){0.f, 0.f, 0.f, 0.f};

    for (int k0 = 0; k0 < 512; k0 += 32) {
        // A-stage with fused gate transform
        short8 vP = *(const short8*)(pP + k0);
        short8 vC = *(const short8*)(pC + k0);
        short8 vR = *(const short8*)(pR + k0);
        short8 g8;
        #pragma unroll
        for (int e = 0; e < 8; e++) {
            float delta = softplus_f(s2f(vP[e]));
            float xssm = delta * s2f(vC[e]) * cbv;
            g8[e] = f2s(silu_f(xssm) * s2f(vR[e]));
        }
        *(short8*)aDst = g8;
        #pragma unroll
        for (int g = 0; g < 4; g++) gl_lds16(bP[g] + k0, bL[g]);
        __syncthreads();
        short8 af[4], bfv[4];
        #pragma unroll
        for (int i = 0; i < 4; i++) af[i] = *(const short8*)&As[(i * 16 + fr) * 32 + quad * 8];
        #pragma unroll
        for (int j = 0; j < 4; j++) bfv[j] = *(const short8*)&Bs[(wn + j * 16 + fr) * 32 + quad * 8];
        #pragma unroll
        for (int i = 0; i < 4; i++)
            #pragma unroll
            for (int j = 0; j < 4; j++)
                acc[i][j] = __builtin_amdgcn_mfma_f32_16x16x32_bf16(af[i], bfv[j], acc[i][j], 0, 0, 0);
        __syncthreads();
    }
    #pragma unroll
    for (int j = 0; j < 4; j++) {
        float bv = bias[wn + j * 16 + fr];
        #pragma unroll
        for (int i = 0; i < 4; i++)
            #pragma unroll
            for (int r = 0; r < 4; r++) acc[i][j][r] += bv;
    }
    #pragma unroll
    for (int i = 0; i < 4; i++) {
        #pragma unroll
        for (int r = 0; r < 4; r++) {
            float s = 0.f;
            #pragma unroll
            for (int j = 0; j < 4; j++) s += acc[i][j][r] * acc[i][j][r];
            #pragma unroll
            for (int o = 8; o > 0; o >>= 1) s += __shfl_xor(s, o);
            if (fr == 0) red[wave][i * 16 + quad * 4 + r] = s;
        }
    }
    __syncthreads();
    if (tid < 64) {
        float tot = red[0][tid] + red[1][tid] + red[2][tid] + red[3][tid];
        scl[tid] = rsqrtf(tot * (1.0f / CT) + 1e-5f);
    }
    __syncthreads();
    #pragma unroll
    for (int j = 0; j < 4; j++) {
        int n = wn + j * 16 + fr;
        float w = nw[n];
        #pragma unroll
        for (int i = 0; i < 4; i++) {
            int rl = i * 16 + quad * 4;
            #pragma unroll
            for (int r = 0; r < 4; r++) {
                float v = acc[i][j][r];
                Xo[(size_t)(m0 + rl + r) * CT + n] = f2b(v);
                XNo[(size_t)(m0 + rl + r) * CT + n] = f2b(v * scl[rl + r] * w);
            }
        }
    }
}

// ---- proj GEMM (K=256, N=256) with fused de-norm + transpose to fp32 out ----
__global__ __launch_bounds__(256) void proj_out_kernel(const bf16* __restrict__ A,
                                                       const bf16* __restrict__ Wt,
                                                       const float* __restrict__ bias,
                                                       const float* __restrict__ means,
                                                       const float* __restrict__ stdev,
                                                       float* __restrict__ out) {
    __shared__ __align__(16) short As[128 * 32];
    __shared__ __align__(16) short Bs[128 * 32];
    const int tid = threadIdx.x;
    const int lane = tid & 63;
    const int wave = tid >> 6;
    const int m0 = blockIdx.x * 128, n0 = blockIdx.y * 128;

    const int srow0 = wave * 32;
    const int lrow = lane >> 2;
    const int lcol = (lane & 3) * 8;
    const bf16* aP0 = A + (size_t)(m0 + srow0 + lrow) * 256 + lcol;
    const bf16* aP1 = A + (size_t)(m0 + srow0 + 16 + lrow) * 256 + lcol;
    const bf16* bP0 = Wt + (size_t)(n0 + srow0 + lrow) * 256 + lcol;
    const bf16* bP1 = Wt + (size_t)(n0 + srow0 + 16 + lrow) * 256 + lcol;
    short* aL0 = &As[srow0 * 32];
    short* aL1 = &As[(srow0 + 16) * 32];
    short* bL0 = &Bs[srow0 * 32];
    short* bL1 = &Bs[(srow0 + 16) * 32];

    const int wm = (wave & 1) * 64, wn = (wave >> 1) * 64;
    const int fr = lane & 15, quad = lane >> 4;

    floatx4 acc[4][4];
    #pragma unroll
    for (int i = 0; i < 4; i++)
        #pragma unroll
        for (int j = 0; j < 4; j++) acc[i][j] = (floatx4){0.f, 0.f, 0.f, 0.f};

    for (int k0 = 0; k0 < 256; k0 += 32) {
        gl_lds16(aP0 + k0, aL0);
        gl_lds16(aP1 + k0, aL1);
        gl_lds16(bP0 + k0, bL0);
        gl_lds16(bP1 + k0, bL1);
        __syncthreads();
        short8 af[4], bfv[4];
        #pragma unroll
        for (int i = 0; i < 4; i++) af[i] = *(const short8*)&As[(wm + i * 16 + fr) * 32 + quad * 8];
        #pragma unroll
        for (int j = 0; j < 4; j++) bfv[j] = *(const short8*)&Bs[(wn + j * 16 + fr) * 32 + quad * 8];
        #pragma unroll
        for (int i = 0; i < 4; i++)
            #pragma unroll
            for (int j = 0; j < 4; j++)
                acc[i][j] = __builtin_amdgcn_mfma_f32_16x16x32_bf16(af[i], bfv[j], acc[i][j], 0, 0, 0);
        __syncthreads();
    }
    #pragma unroll
    for (int j = 0; j < 4; j++) {
        int t = n0 + wn + j * 16 + fr;
        float bv = bias[t];
        #pragma unroll
        for (int i = 0; i < 4; i++) {
            int mb = m0 + wm + i * 16 + quad * 4;
            int b = mb >> 9;
            int nv = mb & 511;
            if (nv < CN) {
                floatx4 o;
                #pragma unroll
                for (int r = 0; r < 4; r++) {
                    int sn = b * CN + nv + r;
                    o[r] = (acc[i][j][r] + bv) * stdev[sn] + means[sn];
                }
                *(floatx4*)(out + ((size_t)(b * CT + t)) * CN + nv) = o;
            }
        }
    }
}

extern "C" void kernel_launch(void* const* d_in, const int* in_sizes, int n_in,
                              void* d_out, int out_size, void* d_ws, size_t ws_size,
                              hipStream_t stream) {
    const float* x_enc  = (const float*)d_in[0];
    const float* x_mark = (const float*)d_in[1];
    const float* norm_w = (const float*)d_in[4];
    const float* inp_W  = (const float*)d_in[5];
    const float* inp_b  = (const float*)d_in[6];
    const float* conv_W = (const float*)d_in[7];
    const float* conv_b = (const float*)d_in[8];
    const float* convlin_W = (const float*)d_in[9];
    const float* convlin_b = (const float*)d_in[10];
    const float* fc1_W = (const float*)d_in[11];
    const float* fc1_b = (const float*)d_in[12];
    const float* fc2_W = (const float*)d_in[13];
    const float* fc2_b = (const float*)d_in[14];
    const float* fc3_W = (const float*)d_in[15];
    const float* fc3_b = (const float*)d_in[16];
    const float* D_W   = (const float*)d_in[17];
    const float* D_b   = (const float*)d_in[18];
    const float* out_W = (const float*)d_in[19];
    const float* out_b = (const float*)d_in[20];
    const float* proj_W = (const float*)d_in[21];
    const float* proj_b = (const float*)d_in[22];

    // ---- workspace layout (~92 MB) ----
    char* ws = (char*)d_ws;
    float* MEANS = (float*)(ws);
    float* STDEV = (float*)(ws + 65536);
    float* CBv   = (float*)(ws + 131072);    // 64 KB slot (16384 floats)
    bf16* wt = (bf16*)(ws + 196608);
    bf16* wt_g1      = wt;                   // 3 x [1024][256]  (inp^T | D^T)
    bf16* wt_g3      = wt + 786432;          // 3 x [fc1^T 512x512 | fc2⊕fc3 512x512]
    bf16* wt_convlin = wt + 2359296;         // 3 x [512][512]
    bf16* wt_out     = wt + 3145728;         // 3 x [256][512]
    bf16* wt_proj    = wt + 3538944;         // [256][256]
    bf16* wt_conv    = wt + 3604480;         // 3 x [3][512][512]
    bf16* xpT = (bf16*)(ws + 12124160);      // [32][528][512] = 17.3 MB
    const size_t POOLB = 16777216;
    const size_t HALF = 16384 * 256;
    bf16* pool[4] = {
        (bf16*)(ws + 29425664),
        (bf16*)(ws + 29425664 + POOLB),
        (bf16*)(ws + 29425664 + 2 * POOLB),
        (bf16*)(ws + 29425664 + 3 * POOLB),
    };
    float* out = (float*)d_out;

    // ---- prepack ----
    P8 p;
    p.s[0] = inp_W;  p.d[0] = wt_g1;
    p.s[1] = D_W;    p.d[1] = wt_g1 + 131072;
    p.s[2] = fc1_W;  p.d[2] = wt_g3;
    p.s[3] = fc2_W;  p.d[3] = wt_g3 + 262144;   // interleaved rows 2c
    p.s[4] = fc3_W;  p.d[4] = wt_g3 + 262144;   // interleaved rows 2c+1
    p.s[5] = convlin_W; p.d[5] = wt_convlin;
    p.s[6] = out_W;  p.d[6] = wt_out;
    p.s[7] = proj_W; p.d[7] = wt_proj;
    prepack_all_kernel<<<3520, 256, 0, stream>>>(p);
    convpack_kernel<<<(CONVN + 32768 + MROWS + 255) / 256, 256, 0, stream>>>(
        conv_W, wt_conv, xpT, CBv);

    // ---- fused stats + build + rmsnorm(iter0): xn -> pool[0].hi ----
    buildx_rms_kernel<<<256, 256, 0, stream>>>(x_enc, x_mark, norm_w, MEANS, STDEV,
                                               pool[0] + HALF);

    // 4-pool rotation: A (x,xn) | xc/P | xres | out(x_next,xn_next)
    int ia = 0, ico = 1, ires = 2, iout = 3;
    // roles per iteration: conv writes xc into A (xn dead after mgemm<1>);
    // convlin -> pool[ico]; mgemm<3> P -> A; gemm_rms reads A,ico,ires writes iout.
    for (int i = 0; i < 3; i++) {
        bf16* A  = pool[ia];
        bf16* XCO = pool[ico];
        bf16* XRES = pool[ires];
        bf16* OUTP = pool[iout];
        bf16* XN = A + HALF;

        // [xp|xres] = xn @ [inp|D] + b : xp -> xpT (transposed), xres -> XRES
        mgemm_kernel<1><<<dim3(128, 8), 256, 0, stream>>>(
            XN, wt_g1 + (size_t)i * 262144, inp_b + i * CT2, D_b + i * CT2, nullptr,
            xpT, XRES, nullptr, 256, 1024);
        // xc = silu(conv(xp)) -> A
        conv_mfma_kernel<<<512, 256, 0, stream>>>(wt_conv + (size_t)i * 786432, xpT,
                                                  conv_b + i * CF, A);
        // xco = xc @ convlin + b -> XCO
        mgemm_kernel<0><<<dim3(128, 4), 256, 0, stream>>>(
            A, wt_convlin + (size_t)i * 262144, convlin_b + i * CT2, nullptr, nullptr,
            XCO, nullptr, nullptr, 512, 512);
        // [P | cb-atomics] = xco @ [fc1 | fc2⊕fc3] : P -> A, cb -> CBv
        mgemm_kernel<3><<<dim3(128, 8), 256, 0, stream>>>(
            XCO, wt_g3 + (size_t)i * 524288, fc1_b + i * CT2, fc2_b + i * CT, fc3_b + i * CT,
            A, nullptr, CBv, 512, 1024);
        // x_next = gate(P,xco,cb,xres) @ out_W + b -> OUTP.lo ; rmsnorm -> OUTP.hi
        gemm_rms_kernel<<<256, 256, 0, stream>>>(
            A, XCO, XRES, CBv, wt_out + (size_t)i * 131072, out_b + i * CT,
            norm_w + ((i + 1) % 3) * CT, OUTP, OUTP + HALF);

        // rotate: next A = OUTP; others recycle
        int na = iout, nco = ia, nres = ico, nout = ires;
        ia = na; ico = nco; ires = nres; iout = nout;
    }

    // x_final in pool[ia] (lo). dec = x @ proj_W + b, de-norm + transpose to out
    proj_out_kernel<<<dim3(128, 2), 256, 0, stream>>>(
        pool[ia], wt_proj, proj_b, MEANS, STDEV, out);
}

// Round 9
// 581.165 us; speedup vs baseline: 1.1546x; 1.1292x over previous
//
#include <hip/hip_runtime.h>
#include <hip/hip_bf16.h>
#include <math.h>

typedef __hip_bfloat16 bf16;
typedef short short8 __attribute__((ext_vector_type(8)));
typedef short short4v __attribute__((ext_vector_type(4)));
typedef float floatx4 __attribute__((ext_vector_type(4)));

constexpr int CB_ = 32;
constexpr int CT = 256;
constexpr int CF = 512;
constexpr int CN = 508;
constexpr int CM = 4;
constexpr int CT2 = 512;
constexpr int MROWS = CB_ * CF;  // 16384
constexpr int PADL = 528;       // xpT rows/batch: 0 pad, 1..512 live, 513 pad, rest slack

__device__ __forceinline__ float b2f(bf16 v) { return __bfloat162float(v); }
__device__ __forceinline__ bf16 f2b(float v) { return __float2bfloat16(v); }
__device__ __forceinline__ float s2f(short s) {
    unsigned u = ((unsigned)(unsigned short)s) << 16;
    return __builtin_bit_cast(float, u);
}
__device__ __forceinline__ short f2s(float v) {
    bf16 t = __float2bfloat16(v);
    return __builtin_bit_cast(short, t);
}
// fast-math variants: v_exp_f32/v_log_f32 based; error << bf16 rounding
__device__ __forceinline__ float silu_f(float x) { return x / (1.0f + __expf(-x)); }
__device__ __forceinline__ float softplus_f(float x) {
    return fmaxf(x, 0.0f) + __logf(1.0f + __expf(-fabsf(x)));
}

__device__ __forceinline__ void gl_lds16(const bf16* g, short* l) {
    __builtin_amdgcn_global_load_lds(
        (const __attribute__((address_space(1))) unsigned int*)(g),
        (__attribute__((address_space(3))) unsigned int*)(l), 16, 0, 0);
}

// ---- merged weight prepack: 8 matrices, W(KxN fp32) -> Wt(NxK bf16).
// fc2/fc3 are INTERLEAVED into one [512][512] region: dst row = 2c (fc2) / 2c+1 (fc3).
struct P8 { const float* s[8]; bf16* d[8]; };
__global__ __launch_bounds__(256) void prepack_all_kernel(P8 p) {
    const int Ks[8]   = {256, 256, 512, 512, 512, 512, 512, 256};
    const int Ns[8]   = {512, 512, 512, 256, 256, 512, 256, 256};
    const int zs[8]   = {3, 3, 3, 3, 3, 3, 3, 1};
    const int dstr[8] = {262144, 262144, 524288, 524288, 524288, 262144, 131072, 65536};
    const int rml[8]  = {1, 1, 1, 2, 2, 1, 1, 1};
    const int rad[8]  = {0, 0, 0, 0, 1, 0, 0, 0};
    int bid = blockIdx.x;
    int m = 0, acc = 0;
    for (m = 0; m < 8; m++) {
        int c = (Ns[m] >> 5) * (Ks[m] >> 5) * zs[m];
        if (bid < acc + c) break;
        acc += c;
    }
    int lid = bid - acc;
    int K = Ks[m], N = Ns[m];
    int tx = N >> 5, ty = K >> 5;
    int z = lid / (tx * ty), rem = lid % (tx * ty);
    int k0 = (rem / tx) * 32, n0 = (rem % tx) * 32;
    const float* s = p.s[m] + (size_t)z * K * N;
    bf16* d = p.d[m] + (size_t)z * dstr[m];
    int mul = rml[m], add = rad[m];
    __shared__ float Ts[32][33];
    for (int e = threadIdx.x; e < 1024; e += 256) {
        int r = e >> 5, c = e & 31;
        Ts[r][c] = s[(size_t)(k0 + r) * N + n0 + c];
    }
    __syncthreads();
    for (int e = threadIdx.x; e < 1024; e += 256) {
        int r = e >> 5, c = e & 31;
        d[(size_t)((n0 + r) * mul + add) * K + k0 + c] = f2b(Ts[c][r]);
    }
}

// ---- conv weight pack + xpT pad-row zero + CBv zero (merged) ----
constexpr int CONVN = 3 * 3 * 512 * 512;  // 2359296
__global__ void convpack_kernel(const float* __restrict__ src, bf16* __restrict__ dst,
                                bf16* __restrict__ xpT, float* __restrict__ CBv) {
    int idx = blockIdx.x * 256 + threadIdx.x;
    if (idx < CONVN) {
        int ci = idx & 511;
        int co = (idx >> 9) & 511;
        int it = idx >> 18;
        int tap = it % 3, ib = it / 3;
        dst[idx] = f2b(src[(((size_t)(ib * 512 + co)) * 512 + ci) * 3 + tap]);
    } else if (idx < CONVN + 32768) {
        int j = idx - CONVN;
        int ci = j & 511;
        int w = (j >> 9) & 1;
        int b = j >> 10;
        xpT[((size_t)b * PADL + (w ? 513 : 0)) * 512 + ci] = f2b(0.0f);
    } else if (idx < CONVN + 32768 + MROWS) {
        CBv[idx - CONVN - 32768] = 0.0f;
    }
}

// ---- fused stats + build_x + rmsnorm (iter 0), coalesced via LDS tile ----
__global__ __launch_bounds__(256) void buildx_rms_kernel(
    const float* __restrict__ xe, const float* __restrict__ xm,
    const float* __restrict__ nw, float* __restrict__ means, float* __restrict__ stdev,
    bf16* __restrict__ XN) {
    __shared__ float L[256][65];
    __shared__ float red_s[4][64], red_q[4][64];
    __shared__ float stat_m[64], stat_i[64], scl[64];
    int blk = blockIdx.x;
    int b = blk >> 3, f0 = (blk & 7) * 64;
    int tid = threadIdx.x;
    int j = tid & 63, tq = tid >> 6;
    int f = f0 + j;
    float ps = 0.f, pq = 0.f;
    const float* xep = xe + (size_t)b * CT * CN + f;
    const float* xmp = xm + (size_t)b * CT * CM + (f - CN);
    #pragma unroll 4
    for (int tt = 0; tt < 64; tt++) {
        int t = tq * 64 + tt;
        float v = (f < CN) ? xep[(size_t)t * CN] : xmp[(size_t)t * CM];
        L[t][j] = v;
        ps += v;
        pq += v * v;
    }
    red_s[tq][j] = ps;
    red_q[tq][j] = pq;
    __syncthreads();
    if (tid < 64) {
        int ff = f0 + tid;
        float s = red_s[0][tid] + red_s[1][tid] + red_s[2][tid] + red_s[3][tid];
        float q = red_q[0][tid] + red_q[1][tid] + red_q[2][tid] + red_q[3][tid];
        float mean, isd, msq;
        if (ff < CN) {
            mean = s * (1.0f / 256.0f);
            float var = fmaxf(q * (1.0f / 256.0f) - mean * mean, 0.0f);
            float sd = sqrtf(var + 1e-5f);
            isd = 1.0f / sd;
            means[b * CN + ff] = mean;
            stdev[b * CN + ff] = sd;
            msq = var / (var + 1e-5f);
        } else {
            mean = 0.0f;
            isd = 1.0f;
            msq = q * (1.0f / 256.0f);
        }
        stat_m[tid] = mean;
        stat_i[tid] = isd;
        scl[tid] = rsqrtf(msq + 1e-5f);
    }
    __syncthreads();
    bf16* outp = XN + ((size_t)(b * 512 + f0)) * 256;
    int t = tid;
    float w = nw[t];
    #pragma unroll 4
    for (int fp = 0; fp < 64; fp++) {
        float val = (L[t][fp] - stat_m[fp]) * stat_i[fp];
        outp[(size_t)fp * 256 + t] = f2b(val * scl[fp] * w);
    }
}

// ---- MFMA GEMM (m97 structure). MODE 0: plain. MODE 1: [inp|D] split epilogue.
// MODE 3: [fc1 | fc2⊕fc3-interleaved]: n<512 -> P stores; n>=512 -> cb atomics only.
template <int MODE>
__global__ __launch_bounds__(256) void mgemm_kernel(const bf16* __restrict__ A,
                                                    const bf16* __restrict__ Wt,
                                                    const float* __restrict__ b1,
                                                    const float* __restrict__ b2,
                                                    const float* __restrict__ b3,
                                                    bf16* __restrict__ o1,
                                                    bf16* __restrict__ o2,
                                                    float* __restrict__ CBv,
                                                    int K, int Ncols) {
    __shared__ __align__(16) short As[128 * 32];
    __shared__ __align__(16) short Bs[128 * 32];
    const int tid = threadIdx.x;
    const int lane = tid & 63;
    const int wave = tid >> 6;
    const int m0 = blockIdx.x * 128, n0 = blockIdx.y * 128;

    const int srow0 = wave * 32;
    const int lrow = lane >> 2;
    const int lcol = (lane & 3) * 8;

    const bf16* aP0 = A + (size_t)(m0 + srow0 + lrow) * K + lcol;
    const bf16* aP1 = A + (size_t)(m0 + srow0 + 16 + lrow) * K + lcol;
    const bf16* bP0 = Wt + (size_t)(n0 + srow0 + lrow) * K + lcol;
    const bf16* bP1 = Wt + (size_t)(n0 + srow0 + 16 + lrow) * K + lcol;
    short* aL0 = &As[srow0 * 32];
    short* aL1 = &As[(srow0 + 16) * 32];
    short* bL0 = &Bs[srow0 * 32];
    short* bL1 = &Bs[(srow0 + 16) * 32];

    const int wm = (wave & 1) * 64, wn = (wave >> 1) * 64;
    const int fr = lane & 15, quad = lane >> 4;

    floatx4 acc[4][4];
    #pragma unroll
    for (int i = 0; i < 4; i++)
        #pragma unroll
        for (int j = 0; j < 4; j++) acc[i][j] = (floatx4){0.f, 0.f, 0.f, 0.f};

    for (int k0 = 0; k0 < K; k0 += 32) {
        gl_lds16(aP0 + k0, aL0);
        gl_lds16(aP1 + k0, aL1);
        gl_lds16(bP0 + k0, bL0);
        gl_lds16(bP1 + k0, bL1);
        __syncthreads();
        short8 af[4], bfv[4];
        #pragma unroll
        for (int i = 0; i < 4; i++) af[i] = *(const short8*)&As[(wm + i * 16 + fr) * 32 + quad * 8];
        #pragma unroll
        for (int j = 0; j < 4; j++) bfv[j] = *(const short8*)&Bs[(wn + j * 16 + fr) * 32 + quad * 8];
        #pragma unroll
        for (int i = 0; i < 4; i++)
            #pragma unroll
            for (int j = 0; j < 4; j++)
                acc[i][j] = __builtin_amdgcn_mfma_f32_16x16x32_bf16(af[i], bfv[j], acc[i][j], 0, 0, 0);
        __syncthreads();
    }

    if (MODE == 0) {
        #pragma unroll
        for (int j = 0; j < 4; j++) {
            int n = n0 + wn + j * 16 + fr;
            float bv = b1[n];
            #pragma unroll
            for (int i = 0; i < 4; i++) {
                int mb = m0 + wm + i * 16 + quad * 4;
                #pragma unroll
                for (int r = 0; r < 4; r++)
                    o1[(size_t)(mb + r) * Ncols + n] = f2b(acc[i][j][r] + bv);
            }
        }
    } else if (MODE == 1) {
        if (n0 + wn < 512) {
            int b = (m0 + wm) >> 9;
            #pragma unroll
            for (int j = 0; j < 4; j++) {
                int n = n0 + wn + j * 16 + fr;
                float bv = b1[n];
                bf16* dst = o1 + ((size_t)b * PADL + n + 1) * 512;
                #pragma unroll
                for (int i = 0; i < 4; i++) {
                    int ci = (m0 + wm + i * 16 + quad * 4) & 511;
                    short4v pk;
                    #pragma unroll
                    for (int r = 0; r < 4; r++) pk[r] = f2s(acc[i][j][r] + bv);
                    *(short4v*)(dst + ci) = pk;
                }
            }
        } else {
            #pragma unroll
            for (int j = 0; j < 4; j++) {
                int n = n0 + wn + j * 16 + fr;
                float bv = b2[n - 512];
                #pragma unroll
                for (int i = 0; i < 4; i++) {
                    int mb = m0 + wm + i * 16 + quad * 4;
                    #pragma unroll
                    for (int r = 0; r < 4; r++)
                        o2[(size_t)(mb + r) * 512 + (n - 512)] = f2b(silu_f(acc[i][j][r] + bv));
                }
            }
        }
    } else {  // MODE 3
        if (n0 + wn < 512) {
            #pragma unroll
            for (int j = 0; j < 4; j++) {
                int n = n0 + wn + j * 16 + fr;
                float bv = b1[n];
                #pragma unroll
                for (int i = 0; i < 4; i++) {
                    int mb = m0 + wm + i * 16 + quad * 4;
                    #pragma unroll
                    for (int r = 0; r < 4; r++)
                        o1[(size_t)(mb + r) * 512 + n] = f2b(acc[i][j][r] + bv);
                }
            }
        } else {
            int nnb = (n0 - 512) + wn;
            float bv[4];
            #pragma unroll
            for (int j = 0; j < 4; j++) {
                int nn = nnb + j * 16 + fr;
                int c = nn >> 1;
                bv[j] = (fr & 1) ? b3[c] : b2[c];
            }
            #pragma unroll
            for (int i = 0; i < 4; i++) {
                #pragma unroll
                for (int r = 0; r < 4; r++) {
                    float s = 0.f;
                    #pragma unroll
                    for (int j = 0; j < 4; j++) {
                        float v = acc[i][j][r] + bv[j];
                        s += v * __shfl_xor(v, 1);
                    }
                    s += __shfl_xor(s, 2);
                    s += __shfl_xor(s, 4);
                    s += __shfl_xor(s, 8);
                    if (fr == 0)
                        atomicAdd(&CBv[m0 + wm + i * 16 + quad * 4 + r], s * 0.5f);
                }
            }
        }
    }
}

// ---- conv as implicit MFMA GEMM (R6 version): 128x128 tile, 512 blocks,
// single B-stage for all 3 taps, XCD swizzle ----
__global__ __launch_bounds__(256) void conv_mfma_kernel(const bf16* __restrict__ Wc,
                                                        const bf16* __restrict__ xpT,
                                                        const float* __restrict__ bias,
                                                        bf16* __restrict__ Out) {
    __shared__ __align__(16) short As[3 * 128 * 32];
    __shared__ __align__(16) short Bs[144 * 32];
    const int tid = threadIdx.x;
    const int lane = tid & 63;
    const int wave = tid >> 6;
    int bx = blockIdx.x;
    int xcd = bx & 7, g = bx >> 3;
    int mt = g & 3;
    int id = xcd * 16 + (g >> 2);
    int nt = id & 3, b = id >> 2;
    const int m0 = mt * 128, n0 = nt * 128;
    const bf16* xb = xpT + (size_t)b * PADL * 512;

    const int lrow = lane >> 2;
    const int lcol = (lane & 3) * 8;
    const int wm = (wave & 1) * 64, wn = (wave >> 1) * 64;
    const int fr = lane & 15, quad = lane >> 4;

    floatx4 acc[4][4];
    #pragma unroll
    for (int i = 0; i < 4; i++)
        #pragma unroll
        for (int j = 0; j < 4; j++) acc[i][j] = (floatx4){0.f, 0.f, 0.f, 0.f};

    for (int k0 = 0; k0 < 512; k0 += 32) {
        for (int ga = wave; ga < 24; ga += 4) {
            int tap = ga >> 3, rg = ga & 7;
            gl_lds16(Wc + (size_t)tap * 262144 + (size_t)(m0 + rg * 16 + lrow) * 512 + k0 + lcol,
                     &As[ga * 512]);
        }
        for (int gb = wave; gb < 9; gb += 4) {
            gl_lds16(xb + (size_t)(n0 + gb * 16 + lrow) * 512 + k0 + lcol, &Bs[gb * 512]);
        }
        __syncthreads();
        #pragma unroll
        for (int tap = 0; tap < 3; tap++) {
            short8 af[4], bfv[4];
            #pragma unroll
            for (int i = 0; i < 4; i++)
                af[i] = *(const short8*)&As[tap * 4096 + (wm + i * 16 + fr) * 32 + quad * 8];
            #pragma unroll
            for (int j = 0; j < 4; j++)
                bfv[j] = *(const short8*)&Bs[(wn + j * 16 + fr + tap) * 32 + quad * 8];
            #pragma unroll
            for (int i = 0; i < 4; i++)
                #pragma unroll
                for (int j = 0; j < 4; j++)
                    acc[i][j] = __builtin_amdgcn_mfma_f32_16x16x32_bf16(af[i], bfv[j], acc[i][j], 0, 0, 0);
        }
        __syncthreads();
    }
    bf16* ob = Out + (size_t)b * CF * CT2;
    #pragma unroll
    for (int i = 0; i < 4; i++) {
        int mb = m0 + wm + i * 16 + quad * 4;
        #pragma unroll
        for (int r = 0; r < 4; r++) {
            float bv = bias[mb + r];
            #pragma unroll
            for (int j = 0; j < 4; j++) {
                int n = n0 + wn + j * 16 + fr;
                ob[(size_t)(mb + r) * CT2 + n] = f2b(silu_f(acc[i][j][r] + bv));
            }
        }
    }
}

// ---- standalone s6 gate: P = silu(softplus(P)*xco*cb)*xres, in-place, short8-vec.
// All 64 readers of CBv[row] are one wave -> lane0 self-zeroes after broadcast read.
__global__ __launch_bounds__(256) void gate_kernel(bf16* __restrict__ P,
                                                   const bf16* __restrict__ xco,
                                                   float* __restrict__ CBv,
                                                   const bf16* __restrict__ xres) {
    int idx = blockIdx.x * 256 + threadIdx.x;   // 1M threads, 8 elem each
    size_t base = (size_t)idx * 8;
    int row = idx >> 6;                          // 64 threads per 512-elem row
    float cb = CBv[row];
    if ((idx & 63) == 0) CBv[row] = 0.0f;        // wave-broadcast read precedes write
    short8 vP = *(const short8*)((const short*)P + base);
    short8 vC = *(const short8*)((const short*)xco + base);
    short8 vR = *(const short8*)((const short*)xres + base);
    short8 g8;
    #pragma unroll
    for (int e = 0; e < 8; e++) {
        float delta = softplus_f(s2f(vP[e]));
        float xssm = delta * s2f(vC[e]) * cb;
        g8[e] = f2s(silu_f(xssm) * s2f(vR[e]));
    }
    *(short8*)((short*)P + base) = g8;
}

// ---- out-GEMM (K=512, N=256 full width) with FUSED rmsnorm epilogue (R6 form) ----
__global__ __launch_bounds__(256) void gemm_rms_kernel(const bf16* __restrict__ A,
                                                       const bf16* __restrict__ Wt,
                                                       const float* __restrict__ bias,
                                                       const float* __restrict__ nw,
                                                       bf16* __restrict__ Xo,
                                                       bf16* __restrict__ XNo) {
    __shared__ __align__(16) short As[64 * 32];
    __shared__ __align__(16) short Bs[256 * 32];
    __shared__ float red[4][64];
    __shared__ float scl[64];
    const int tid = threadIdx.x;
    const int lane = tid & 63;
    const int wave = tid >> 6;
    const int m0 = blockIdx.x * 64;

    const int lrow = lane >> 2;
    const int lcol = (lane & 3) * 8;
    const bf16* aP = A + (size_t)(m0 + wave * 16 + lrow) * 512 + lcol;
    short* aL = &As[wave * 16 * 32];
    const bf16* bP[4];
    short* bL[4];
    #pragma unroll
    for (int g = 0; g < 4; g++) {
        int r0 = (wave * 4 + g) * 16;
        bP[g] = Wt + (size_t)(r0 + lrow) * 512 + lcol;
        bL[g] = &Bs[r0 * 32];
    }
    const int wn = wave * 64;
    const int fr = lane & 15, quad = lane >> 4;

    floatx4 acc[4][4];
    #pragma unroll
    for (int i = 0; i < 4; i++)
        #pragma unroll
        for (int j = 0; j < 4; j++) acc[i][j] = (floatx4){0.f, 0.f, 0.f, 0.f};

    for (int k0 = 0; k0 < 512; k0 += 32) {
        gl_lds16(aP + k0, aL);
        #pragma unroll
        for (int g = 0; g < 4; g++) gl_lds16(bP[g] + k0, bL[g]);
        __syncthreads();
        short8 af[4], bfv[4];
        #pragma unroll
        for (int i = 0; i < 4; i++) af[i] = *(const short8*)&As[(i * 16 + fr) * 32 + quad * 8];
        #pragma unroll
        for (int j = 0; j < 4; j++) bfv[j] = *(const short8*)&Bs[(wn + j * 16 + fr) * 32 + quad * 8];
        #pragma unroll
        for (int i = 0; i < 4; i++)
            #pragma unroll
            for (int j = 0; j < 4; j++)
                acc[i][j] = __builtin_amdgcn_mfma_f32_16x16x32_bf16(af[i], bfv[j], acc[i][j], 0, 0, 0);
        __syncthreads();
    }
    #pragma unroll
    for (int j = 0; j < 4; j++) {
        float bv = bias[wn + j * 16 + fr];
        #pragma unroll
        for (int i = 0; i < 4; i++)
            #pragma unroll
            for (int r = 0; r < 4; r++) acc[i][j][r] += bv;
    }
    #pragma unroll
    for (int i = 0; i < 4; i++) {
        #pragma unroll
        for (int r = 0; r < 4; r++) {
            float s = 0.f;
            #pragma unroll
            for (int j = 0; j < 4; j++) s += acc[i][j][r] * acc[i][j][r];
            #pragma unroll
            for (int o = 8; o > 0; o >>= 1) s += __shfl_xor(s, o);
            if (fr == 0) red[wave][i * 16 + quad * 4 + r] = s;
        }
    }
    __syncthreads();
    if (tid < 64) {
        float tot = red[0][tid] + red[1][tid] + red[2][tid] + red[3][tid];
        scl[tid] = rsqrtf(tot * (1.0f / CT) + 1e-5f);
    }
    __syncthreads();
    #pragma unroll
    for (int j = 0; j < 4; j++) {
        int n = wn + j * 16 + fr;
        float w = nw[n];
        #pragma unroll
        for (int i = 0; i < 4; i++) {
            int rl = i * 16 + quad * 4;
            #pragma unroll
            for (int r = 0; r < 4; r++) {
                float v = acc[i][j][r];
                Xo[(size_t)(m0 + rl + r) * CT + n] = f2b(v);
                XNo[(size_t)(m0 + rl + r) * CT + n] = f2b(v * scl[rl + r] * w);
            }
        }
    }
}

// ---- proj GEMM (K=256, N=256) with fused de-norm + transpose to fp32 out ----
__global__ __launch_bounds__(256) void proj_out_kernel(const bf16* __restrict__ A,
                                                       const bf16* __restrict__ Wt,
                                                       const float* __restrict__ bias,
                                                       const float* __restrict__ means,
                                                       const float* __restrict__ stdev,
                                                       float* __restrict__ out) {
    __shared__ __align__(16) short As[128 * 32];
    __shared__ __align__(16) short Bs[128 * 32];
    const int tid = threadIdx.x;
    const int lane = tid & 63;
    const int wave = tid >> 6;
    const int m0 = blockIdx.x * 128, n0 = blockIdx.y * 128;

    const int srow0 = wave * 32;
    const int lrow = lane >> 2;
    const int lcol = (lane & 3) * 8;
    const bf16* aP0 = A + (size_t)(m0 + srow0 + lrow) * 256 + lcol;
    const bf16* aP1 = A + (size_t)(m0 + srow0 + 16 + lrow) * 256 + lcol;
    const bf16* bP0 = Wt + (size_t)(n0 + srow0 + lrow) * 256 + lcol;
    const bf16* bP1 = Wt + (size_t)(n0 + srow0 + 16 + lrow) * 256 + lcol;
    short* aL0 = &As[srow0 * 32];
    short* aL1 = &As[(srow0 + 16) * 32];
    short* bL0 = &Bs[srow0 * 32];
    short* bL1 = &Bs[(srow0 + 16) * 32];

    const int wm = (wave & 1) * 64, wn = (wave >> 1) * 64;
    const int fr = lane & 15, quad = lane >> 4;

    floatx4 acc[4][4];
    #pragma unroll
    for (int i = 0; i < 4; i++)
        #pragma unroll
        for (int j = 0; j < 4; j++) acc[i][j] = (floatx4){0.f, 0.f, 0.f, 0.f};

    for (int k0 = 0; k0 < 256; k0 += 32) {
        gl_lds16(aP0 + k0, aL0);
        gl_lds16(aP1 + k0, aL1);
        gl_lds16(bP0 + k0, bL0);
        gl_lds16(bP1 + k0, bL1);
        __syncthreads();
        short8 af[4], bfv[4];
        #pragma unroll
        for (int i = 0; i < 4; i++) af[i] = *(const short8*)&As[(wm + i * 16 + fr) * 32 + quad * 8];
        #pragma unroll
        for (int j = 0; j < 4; j++) bfv[j] = *(const short8*)&Bs[(wn + j * 16 + fr) * 32 + quad * 8];
        #pragma unroll
        for (int i = 0; i < 4; i++)
            #pragma unroll
            for (int j = 0; j < 4; j++)
                acc[i][j] = __builtin_amdgcn_mfma_f32_16x16x32_bf16(af[i], bfv[j], acc[i][j], 0, 0, 0);
        __syncthreads();
    }
    #pragma unroll
    for (int j = 0; j < 4; j++) {
        int t = n0 + wn + j * 16 + fr;
        float bv = bias[t];
        #pragma unroll
        for (int i = 0; i < 4; i++) {
            int mb = m0 + wm + i * 16 + quad * 4;
            int b = mb >> 9;
            int nv = mb & 511;
            if (nv < CN) {
                floatx4 o;
                #pragma unroll
                for (int r = 0; r < 4; r++) {
                    int sn = b * CN + nv + r;
                    o[r] = (acc[i][j][r] + bv) * stdev[sn] + means[sn];
                }
                *(floatx4*)(out + ((size_t)(b * CT + t)) * CN + nv) = o;
            }
        }
    }
}

extern "C" void kernel_launch(void* const* d_in, const int* in_sizes, int n_in,
                              void* d_out, int out_size, void* d_ws, size_t ws_size,
                              hipStream_t stream) {
    const float* x_enc  = (const float*)d_in[0];
    const float* x_mark = (const float*)d_in[1];
    const float* norm_w = (const float*)d_in[4];
    const float* inp_W  = (const float*)d_in[5];
    const float* inp_b  = (const float*)d_in[6];
    const float* conv_W = (const float*)d_in[7];
    const float* conv_b = (const float*)d_in[8];
    const float* convlin_W = (const float*)d_in[9];
    const float* convlin_b = (const float*)d_in[10];
    const float* fc1_W = (const float*)d_in[11];
    const float* fc1_b = (const float*)d_in[12];
    const float* fc2_W = (const float*)d_in[13];
    const float* fc2_b = (const float*)d_in[14];
    const float* fc3_W = (const float*)d_in[15];
    const float* fc3_b = (const float*)d_in[16];
    const float* D_W   = (const float*)d_in[17];
    const float* D_b   = (const float*)d_in[18];
    const float* out_W = (const float*)d_in[19];
    const float* out_b = (const float*)d_in[20];
    const float* proj_W = (const float*)d_in[21];
    const float* proj_b = (const float*)d_in[22];

    // ---- workspace layout (~92 MB) ----
    char* ws = (char*)d_ws;
    float* MEANS = (float*)(ws);
    float* STDEV = (float*)(ws + 65536);
    float* CBv   = (float*)(ws + 131072);
    bf16* wt = (bf16*)(ws + 196608);
    bf16* wt_g1      = wt;                   // 3 x [1024][256]  (inp^T | D^T)
    bf16* wt_g3      = wt + 786432;          // 3 x [fc1^T 512x512 | fc2⊕fc3 512x512]
    bf16* wt_convlin = wt + 2359296;         // 3 x [512][512]
    bf16* wt_out     = wt + 3145728;         // 3 x [256][512]
    bf16* wt_proj    = wt + 3538944;         // [256][256]
    bf16* wt_conv    = wt + 3604480;         // 3 x [3][512][512]
    bf16* xpT = (bf16*)(ws + 12124160);      // [32][528][512] = 17.3 MB
    const size_t POOLB = 16777216;
    const size_t HALF = 16384 * 256;
    bf16* pool[4] = {
        (bf16*)(ws + 29425664),
        (bf16*)(ws + 29425664 + POOLB),
        (bf16*)(ws + 29425664 + 2 * POOLB),
        (bf16*)(ws + 29425664 + 3 * POOLB),
    };
    float* out = (float*)d_out;

    // ---- prepack ----
    P8 p;
    p.s[0] = inp_W;  p.d[0] = wt_g1;
    p.s[1] = D_W;    p.d[1] = wt_g1 + 131072;
    p.s[2] = fc1_W;  p.d[2] = wt_g3;
    p.s[3] = fc2_W;  p.d[3] = wt_g3 + 262144;   // interleaved rows 2c
    p.s[4] = fc3_W;  p.d[4] = wt_g3 + 262144;   // interleaved rows 2c+1
    p.s[5] = convlin_W; p.d[5] = wt_convlin;
    p.s[6] = out_W;  p.d[6] = wt_out;
    p.s[7] = proj_W; p.d[7] = wt_proj;
    prepack_all_kernel<<<3520, 256, 0, stream>>>(p);
    convpack_kernel<<<(CONVN + 32768 + MROWS + 255) / 256, 256, 0, stream>>>(
        conv_W, wt_conv, xpT, CBv);

    // ---- fused stats + build + rmsnorm(iter0): xn -> pool[0].hi ----
    buildx_rms_kernel<<<256, 256, 0, stream>>>(x_enc, x_mark, norm_w, MEANS, STDEV,
                                               pool[0] + HALF);

    // 4-pool rotation
    int ia = 0, ico = 1, ires = 2, iout = 3;
    for (int i = 0; i < 3; i++) {
        bf16* A  = pool[ia];
        bf16* XCO = pool[ico];
        bf16* XRES = pool[ires];
        bf16* OUTP = pool[iout];
        bf16* XN = A + HALF;

        // [xp|xres] = xn @ [inp|D] + b : xp -> xpT (transposed), xres -> XRES
        mgemm_kernel<1><<<dim3(128, 8), 256, 0, stream>>>(
            XN, wt_g1 + (size_t)i * 262144, inp_b + i * CT2, D_b + i * CT2, nullptr,
            xpT, XRES, nullptr, 256, 1024);
        // xc = silu(conv(xp)) -> A
        conv_mfma_kernel<<<512, 256, 0, stream>>>(wt_conv + (size_t)i * 786432, xpT,
                                                  conv_b + i * CF, A);
        // xco = xc @ convlin + b -> XCO
        mgemm_kernel<0><<<dim3(128, 4), 256, 0, stream>>>(
            A, wt_convlin + (size_t)i * 262144, convlin_b + i * CT2, nullptr, nullptr,
            XCO, nullptr, nullptr, 512, 512);
        // [P | cb-atomics] = xco @ [fc1 | fc2⊕fc3] : P -> A, cb -> CBv
        mgemm_kernel<3><<<dim3(128, 8), 256, 0, stream>>>(
            XCO, wt_g3 + (size_t)i * 524288, fc1_b + i * CT2, fc2_b + i * CT, fc3_b + i * CT,
            A, nullptr, CBv, 512, 1024);
        // gate: in-place on A (also zeroes CBv for next iter)
        gate_kernel<<<4096, 256, 0, stream>>>(A, XCO, CBv, XRES);
        // x_next = gate @ out_W + b -> OUTP.lo ; rmsnorm -> OUTP.hi
        gemm_rms_kernel<<<256, 256, 0, stream>>>(
            A, wt_out + (size_t)i * 131072, out_b + i * CT,
            norm_w + ((i + 1) % 3) * CT, OUTP, OUTP + HALF);

        int na = iout, nco = ia, nres = ico, nout = ires;
        ia = na; ico = nco; ires = nres; iout = nout;
    }

    // x_final in pool[ia] (lo). dec = x @ proj_W + b, de-norm + transpose to out
    proj_out_kernel<<<dim3(128, 2), 256, 0, stream>>>(
        pool[ia], wt_proj, proj_b, MEANS, STDEV, out);
}

// Round 10
// 569.853 us; speedup vs baseline: 1.1775x; 1.0199x over previous
//
#include <hip/hip_runtime.h>
#include <hip/hip_bf16.h>
#include <math.h>

typedef __hip_bfloat16 bf16;
typedef short short8 __attribute__((ext_vector_type(8)));
typedef short short4v __attribute__((ext_vector_type(4)));
typedef float floatx4 __attribute__((ext_vector_type(4)));

constexpr int CB_ = 32;
constexpr int CT = 256;
constexpr int CF = 512;
constexpr int CN = 508;
constexpr int CM = 4;
constexpr int CT2 = 512;
constexpr int MROWS = CB_ * CF;  // 16384
constexpr int PADL = 528;       // xpT rows/batch: 0 pad, 1..512 live, 513 pad, rest slack

__device__ __forceinline__ float b2f(bf16 v) { return __bfloat162float(v); }
__device__ __forceinline__ bf16 f2b(float v) { return __float2bfloat16(v); }
__device__ __forceinline__ float s2f(short s) {
    unsigned u = ((unsigned)(unsigned short)s) << 16;
    return __builtin_bit_cast(float, u);
}
__device__ __forceinline__ short f2s(float v) {
    bf16 t = __float2bfloat16(v);
    return __builtin_bit_cast(short, t);
}
// fast-math: v_exp_f32/v_log_f32; error << bf16 rounding
__device__ __forceinline__ float silu_f(float x) { return x / (1.0f + __expf(-x)); }
__device__ __forceinline__ float softplus_f(float x) {
    return fmaxf(x, 0.0f) + __logf(1.0f + __expf(-fabsf(x)));
}

__device__ __forceinline__ void gl_lds16(const bf16* g, short* l) {
    __builtin_amdgcn_global_load_lds(
        (const __attribute__((address_space(1))) unsigned int*)(g),
        (__attribute__((address_space(3))) unsigned int*)(l), 16, 0, 0);
}

// ---- merged weight prepack: 8 matrices, W(KxN fp32) -> Wt(NxK bf16).
// fc2/fc3 INTERLEAVED into one [512][512] region: dst row = 2c (fc2) / 2c+1 (fc3).
struct P8 { const float* s[8]; bf16* d[8]; };
__global__ __launch_bounds__(256) void prepack_all_kernel(P8 p) {
    const int Ks[8]   = {256, 256, 512, 512, 512, 512, 512, 256};
    const int Ns[8]   = {512, 512, 512, 256, 256, 512, 256, 256};
    const int zs[8]   = {3, 3, 3, 3, 3, 3, 3, 1};
    const int dstr[8] = {262144, 262144, 524288, 524288, 524288, 262144, 131072, 65536};
    const int rml[8]  = {1, 1, 1, 2, 2, 1, 1, 1};
    const int rad[8]  = {0, 0, 0, 0, 1, 0, 0, 0};
    int bid = blockIdx.x;
    int m = 0, acc = 0;
    for (m = 0; m < 8; m++) {
        int c = (Ns[m] >> 5) * (Ks[m] >> 5) * zs[m];
        if (bid < acc + c) break;
        acc += c;
    }
    int lid = bid - acc;
    int K = Ks[m], N = Ns[m];
    int tx = N >> 5, ty = K >> 5;
    int z = lid / (tx * ty), rem = lid % (tx * ty);
    int k0 = (rem / tx) * 32, n0 = (rem % tx) * 32;
    const float* s = p.s[m] + (size_t)z * K * N;
    bf16* d = p.d[m] + (size_t)z * dstr[m];
    int mul = rml[m], add = rad[m];
    __shared__ float Ts[32][33];
    for (int e = threadIdx.x; e < 1024; e += 256) {
        int r = e >> 5, c = e & 31;
        Ts[r][c] = s[(size_t)(k0 + r) * N + n0 + c];
    }
    __syncthreads();
    for (int e = threadIdx.x; e < 1024; e += 256) {
        int r = e >> 5, c = e & 31;
        d[(size_t)((n0 + r) * mul + add) * K + k0 + c] = f2b(Ts[c][r]);
    }
}

// ---- conv weight pack + xpT pad-row zero + CBv zero (merged) ----
constexpr int CONVN = 3 * 3 * 512 * 512;  // 2359296
__global__ void convpack_kernel(const float* __restrict__ src, bf16* __restrict__ dst,
                                bf16* __restrict__ xpT, float* __restrict__ CBv) {
    int idx = blockIdx.x * 256 + threadIdx.x;
    if (idx < CONVN) {
        int ci = idx & 511;
        int co = (idx >> 9) & 511;
        int it = idx >> 18;
        int tap = it % 3, ib = it / 3;
        dst[idx] = f2b(src[(((size_t)(ib * 512 + co)) * 512 + ci) * 3 + tap]);
    } else if (idx < CONVN + 32768) {
        int j = idx - CONVN;
        int ci = j & 511;
        int w = (j >> 9) & 1;
        int b = j >> 10;
        xpT[((size_t)b * PADL + (w ? 513 : 0)) * 512 + ci] = f2b(0.0f);
    } else if (idx < CONVN + 32768 + MROWS) {
        CBv[idx - CONVN - 32768] = 0.0f;
    }
}

// ---- fused stats + build_x + rmsnorm (iter 0), coalesced via LDS tile ----
__global__ __launch_bounds__(256) void buildx_rms_kernel(
    const float* __restrict__ xe, const float* __restrict__ xm,
    const float* __restrict__ nw, float* __restrict__ means, float* __restrict__ stdev,
    bf16* __restrict__ XN) {
    __shared__ float L[256][65];
    __shared__ float red_s[4][64], red_q[4][64];
    __shared__ float stat_m[64], stat_i[64], scl[64];
    int blk = blockIdx.x;
    int b = blk >> 3, f0 = (blk & 7) * 64;
    int tid = threadIdx.x;
    int j = tid & 63, tq = tid >> 6;
    int f = f0 + j;
    float ps = 0.f, pq = 0.f;
    const float* xep = xe + (size_t)b * CT * CN + f;
    const float* xmp = xm + (size_t)b * CT * CM + (f - CN);
    #pragma unroll 4
    for (int tt = 0; tt < 64; tt++) {
        int t = tq * 64 + tt;
        float v = (f < CN) ? xep[(size_t)t * CN] : xmp[(size_t)t * CM];
        L[t][j] = v;
        ps += v;
        pq += v * v;
    }
    red_s[tq][j] = ps;
    red_q[tq][j] = pq;
    __syncthreads();
    if (tid < 64) {
        int ff = f0 + tid;
        float s = red_s[0][tid] + red_s[1][tid] + red_s[2][tid] + red_s[3][tid];
        float q = red_q[0][tid] + red_q[1][tid] + red_q[2][tid] + red_q[3][tid];
        float mean, isd, msq;
        if (ff < CN) {
            mean = s * (1.0f / 256.0f);
            float var = fmaxf(q * (1.0f / 256.0f) - mean * mean, 0.0f);
            float sd = sqrtf(var + 1e-5f);
            isd = 1.0f / sd;
            means[b * CN + ff] = mean;
            stdev[b * CN + ff] = sd;
            msq = var / (var + 1e-5f);
        } else {
            mean = 0.0f;
            isd = 1.0f;
            msq = q * (1.0f / 256.0f);
        }
        stat_m[tid] = mean;
        stat_i[tid] = isd;
        scl[tid] = rsqrtf(msq + 1e-5f);
    }
    __syncthreads();
    bf16* outp = XN + ((size_t)(b * 512 + f0)) * 256;
    int t = tid;
    float w = nw[t];
    #pragma unroll 4
    for (int fp = 0; fp < 64; fp++) {
        float val = (L[t][fp] - stat_m[fp]) * stat_i[fp];
        outp[(size_t)fp * 256 + t] = f2b(val * scl[fp] * w);
    }
}

// ---- MFMA GEMM (m97 structure). MODE 0: plain. MODE 1: [inp|D] split epilogue. ----
template <int MODE>
__global__ __launch_bounds__(256) void mgemm_kernel(const bf16* __restrict__ A,
                                                    const bf16* __restrict__ Wt,
                                                    const float* __restrict__ b1,
                                                    const float* __restrict__ b2,
                                                    bf16* __restrict__ o1,
                                                    bf16* __restrict__ o2,
                                                    int K, int Ncols) {
    __shared__ __align__(16) short As[128 * 32];
    __shared__ __align__(16) short Bs[128 * 32];
    const int tid = threadIdx.x;
    const int lane = tid & 63;
    const int wave = tid >> 6;
    const int m0 = blockIdx.x * 128, n0 = blockIdx.y * 128;

    const int srow0 = wave * 32;
    const int lrow = lane >> 2;
    const int lcol = (lane & 3) * 8;

    const bf16* aP0 = A + (size_t)(m0 + srow0 + lrow) * K + lcol;
    const bf16* aP1 = A + (size_t)(m0 + srow0 + 16 + lrow) * K + lcol;
    const bf16* bP0 = Wt + (size_t)(n0 + srow0 + lrow) * K + lcol;
    const bf16* bP1 = Wt + (size_t)(n0 + srow0 + 16 + lrow) * K + lcol;
    short* aL0 = &As[srow0 * 32];
    short* aL1 = &As[(srow0 + 16) * 32];
    short* bL0 = &Bs[srow0 * 32];
    short* bL1 = &Bs[(srow0 + 16) * 32];

    const int wm = (wave & 1) * 64, wn = (wave >> 1) * 64;
    const int fr = lane & 15, quad = lane >> 4;

    floatx4 acc[4][4];
    #pragma unroll
    for (int i = 0; i < 4; i++)
        #pragma unroll
        for (int j = 0; j < 4; j++) acc[i][j] = (floatx4){0.f, 0.f, 0.f, 0.f};

    for (int k0 = 0; k0 < K; k0 += 32) {
        gl_lds16(aP0 + k0, aL0);
        gl_lds16(aP1 + k0, aL1);
        gl_lds16(bP0 + k0, bL0);
        gl_lds16(bP1 + k0, bL1);
        __syncthreads();
        short8 af[4], bfv[4];
        #pragma unroll
        for (int i = 0; i < 4; i++) af[i] = *(const short8*)&As[(wm + i * 16 + fr) * 32 + quad * 8];
        #pragma unroll
        for (int j = 0; j < 4; j++) bfv[j] = *(const short8*)&Bs[(wn + j * 16 + fr) * 32 + quad * 8];
        #pragma unroll
        for (int i = 0; i < 4; i++)
            #pragma unroll
            for (int j = 0; j < 4; j++)
                acc[i][j] = __builtin_amdgcn_mfma_f32_16x16x32_bf16(af[i], bfv[j], acc[i][j], 0, 0, 0);
        __syncthreads();
    }

    if (MODE == 0) {
        #pragma unroll
        for (int j = 0; j < 4; j++) {
            int n = n0 + wn + j * 16 + fr;
            float bv = b1[n];
            #pragma unroll
            for (int i = 0; i < 4; i++) {
                int mb = m0 + wm + i * 16 + quad * 4;
                #pragma unroll
                for (int r = 0; r < 4; r++)
                    o1[(size_t)(mb + r) * Ncols + n] = f2b(acc[i][j][r] + bv);
            }
        }
    } else {  // MODE 1: [inp|D]
        if (n0 + wn < 512) {
            int b = (m0 + wm) >> 9;
            #pragma unroll
            for (int j = 0; j < 4; j++) {
                int n = n0 + wn + j * 16 + fr;
                float bv = b1[n];
                bf16* dst = o1 + ((size_t)b * PADL + n + 1) * 512;
                #pragma unroll
                for (int i = 0; i < 4; i++) {
                    int ci = (m0 + wm + i * 16 + quad * 4) & 511;
                    short4v pk;
                    #pragma unroll
                    for (int r = 0; r < 4; r++) pk[r] = f2s(acc[i][j][r] + bv);
                    *(short4v*)(dst + ci) = pk;
                }
            }
        } else {
            #pragma unroll
            for (int j = 0; j < 4; j++) {
                int n = n0 + wn + j * 16 + fr;
                float bv = b2[n - 512];
                #pragma unroll
                for (int i = 0; i < 4; i++) {
                    int mb = m0 + wm + i * 16 + quad * 4;
                    #pragma unroll
                    for (int r = 0; r < 4; r++)
                        o2[(size_t)(mb + r) * 512 + (n - 512)] = f2b(silu_f(acc[i][j][r] + bv));
                }
            }
        }
    }
}

// ---- cb GEMM: xco @ [fc2⊕fc3 interleaved], epilogue = cb atomics only ----
__global__ __launch_bounds__(256) void cbgemm_kernel(const bf16* __restrict__ A,
                                                     const bf16* __restrict__ Wt,
                                                     const float* __restrict__ b2,
                                                     const float* __restrict__ b3,
                                                     float* __restrict__ CBv) {
    __shared__ __align__(16) short As[128 * 32];
    __shared__ __align__(16) short Bs[128 * 32];
    const int tid = threadIdx.x;
    const int lane = tid & 63;
    const int wave = tid >> 6;
    const int m0 = blockIdx.x * 128, n0 = blockIdx.y * 128;

    const int srow0 = wave * 32;
    const int lrow = lane >> 2;
    const int lcol = (lane & 3) * 8;
    const bf16* aP0 = A + (size_t)(m0 + srow0 + lrow) * 512 + lcol;
    const bf16* aP1 = A + (size_t)(m0 + srow0 + 16 + lrow) * 512 + lcol;
    const bf16* bP0 = Wt + (size_t)(n0 + srow0 + lrow) * 512 + lcol;
    const bf16* bP1 = Wt + (size_t)(n0 + srow0 + 16 + lrow) * 512 + lcol;
    short* aL0 = &As[srow0 * 32];
    short* aL1 = &As[(srow0 + 16) * 32];
    short* bL0 = &Bs[srow0 * 32];
    short* bL1 = &Bs[(srow0 + 16) * 32];

    const int wm = (wave & 1) * 64, wn = (wave >> 1) * 64;
    const int fr = lane & 15, quad = lane >> 4;

    floatx4 acc[4][4];
    #pragma unroll
    for (int i = 0; i < 4; i++)
        #pragma unroll
        for (int j = 0; j < 4; j++) acc[i][j] = (floatx4){0.f, 0.f, 0.f, 0.f};

    for (int k0 = 0; k0 < 512; k0 += 32) {
        gl_lds16(aP0 + k0, aL0);
        gl_lds16(aP1 + k0, aL1);
        gl_lds16(bP0 + k0, bL0);
        gl_lds16(bP1 + k0, bL1);
        __syncthreads();
        short8 af[4], bfv[4];
        #pragma unroll
        for (int i = 0; i < 4; i++) af[i] = *(const short8*)&As[(wm + i * 16 + fr) * 32 + quad * 8];
        #pragma unroll
        for (int j = 0; j < 4; j++) bfv[j] = *(const short8*)&Bs[(wn + j * 16 + fr) * 32 + quad * 8];
        #pragma unroll
        for (int i = 0; i < 4; i++)
            #pragma unroll
            for (int j = 0; j < 4; j++)
                acc[i][j] = __builtin_amdgcn_mfma_f32_16x16x32_bf16(af[i], bfv[j], acc[i][j], 0, 0, 0);
        __syncthreads();
    }
    // interleaved epilogue: even col = Bmat_c, odd col = Cmat_c
    int nnb = n0 + wn;
    float bv[4];
    #pragma unroll
    for (int j = 0; j < 4; j++) {
        int nn = nnb + j * 16 + fr;
        int c = nn >> 1;
        bv[j] = (fr & 1) ? b3[c] : b2[c];
    }
    #pragma unroll
    for (int i = 0; i < 4; i++) {
        #pragma unroll
        for (int r = 0; r < 4; r++) {
            float s = 0.f;
            #pragma unroll
            for (int j = 0; j < 4; j++) {
                float v = acc[i][j][r] + bv[j];
                s += v * __shfl_xor(v, 1);
            }
            s += __shfl_xor(s, 2);
            s += __shfl_xor(s, 4);
            s += __shfl_xor(s, 8);
            if (fr == 0)
                atomicAdd(&CBv[m0 + wm + i * 16 + quad * 4 + r], s * 0.5f);
        }
    }
}

// ---- fc1 GEMM with FUSED s6 gate epilogue: g = silu(softplus(acc+b1)*xco*cb)*xres ----
__global__ __launch_bounds__(256) void fc1gate_kernel(const bf16* __restrict__ A,
                                                      const bf16* __restrict__ Wt,
                                                      const float* __restrict__ b1,
                                                      const float* __restrict__ CBv,
                                                      const bf16* __restrict__ Xres,
                                                      bf16* __restrict__ G) {
    __shared__ __align__(16) short As[128 * 32];
    __shared__ __align__(16) short Bs[128 * 32];
    const int tid = threadIdx.x;
    const int lane = tid & 63;
    const int wave = tid >> 6;
    const int m0 = blockIdx.x * 128, n0 = blockIdx.y * 128;

    const int srow0 = wave * 32;
    const int lrow = lane >> 2;
    const int lcol = (lane & 3) * 8;
    const bf16* aP0 = A + (size_t)(m0 + srow0 + lrow) * 512 + lcol;
    const bf16* aP1 = A + (size_t)(m0 + srow0 + 16 + lrow) * 512 + lcol;
    const bf16* bP0 = Wt + (size_t)(n0 + srow0 + lrow) * 512 + lcol;
    const bf16* bP1 = Wt + (size_t)(n0 + srow0 + 16 + lrow) * 512 + lcol;
    short* aL0 = &As[srow0 * 32];
    short* aL1 = &As[(srow0 + 16) * 32];
    short* bL0 = &Bs[srow0 * 32];
    short* bL1 = &Bs[(srow0 + 16) * 32];

    const int wm = (wave & 1) * 64, wn = (wave >> 1) * 64;
    const int fr = lane & 15, quad = lane >> 4;

    floatx4 acc[4][4];
    #pragma unroll
    for (int i = 0; i < 4; i++)
        #pragma unroll
        for (int j = 0; j < 4; j++) acc[i][j] = (floatx4){0.f, 0.f, 0.f, 0.f};

    for (int k0 = 0; k0 < 512; k0 += 32) {
        gl_lds16(aP0 + k0, aL0);
        gl_lds16(aP1 + k0, aL1);
        gl_lds16(bP0 + k0, bL0);
        gl_lds16(bP1 + k0, bL1);
        __syncthreads();
        short8 af[4], bfv[4];
        #pragma unroll
        for (int i = 0; i < 4; i++) af[i] = *(const short8*)&As[(wm + i * 16 + fr) * 32 + quad * 8];
        #pragma unroll
        for (int j = 0; j < 4; j++) bfv[j] = *(const short8*)&Bs[(wn + j * 16 + fr) * 32 + quad * 8];
        #pragma unroll
        for (int i = 0; i < 4; i++)
            #pragma unroll
            for (int j = 0; j < 4; j++)
                acc[i][j] = __builtin_amdgcn_mfma_f32_16x16x32_bf16(af[i], bfv[j], acc[i][j], 0, 0, 0);
        __syncthreads();
    }
    // gate epilogue (A doubles as xco)
    #pragma unroll
    for (int i = 0; i < 4; i++) {
        int mb = m0 + wm + i * 16 + quad * 4;
        float cbr[4];
        #pragma unroll
        for (int r = 0; r < 4; r++) cbr[r] = CBv[mb + r];
        #pragma unroll
        for (int j = 0; j < 4; j++) {
            int n = n0 + wn + j * 16 + fr;
            float bv = b1[n];
            #pragma unroll
            for (int r = 0; r < 4; r++) {
                size_t off = (size_t)(mb + r) * 512 + n;
                float delta = softplus_f(acc[i][j][r] + bv);
                float xssm = delta * b2f(A[off]) * cbr[r];
                G[off] = f2b(silu_f(xssm) * b2f(Xres[off]));
            }
        }
    }
}

// ---- conv as implicit MFMA GEMM (R6 form) + CBv zeroing at entry ----
__global__ __launch_bounds__(256) void conv_mfma_kernel(const bf16* __restrict__ Wc,
                                                        const bf16* __restrict__ xpT,
                                                        const float* __restrict__ bias,
                                                        bf16* __restrict__ Out,
                                                        float* __restrict__ CBvZ) {
    __shared__ __align__(16) short As[3 * 128 * 32];
    __shared__ __align__(16) short Bs[144 * 32];
    const int tid = threadIdx.x;
    const int lane = tid & 63;
    const int wave = tid >> 6;
    int bx = blockIdx.x;
    // zero CBv for the upcoming cbgemm (prev fc1gate already consumed it)
    if (bx < 128 && tid < 128) CBvZ[bx * 128 + tid] = 0.0f;
    int xcd = bx & 7, g = bx >> 3;
    int mt = g & 3;
    int id = xcd * 16 + (g >> 2);
    int nt = id & 3, b = id >> 2;
    const int m0 = mt * 128, n0 = nt * 128;
    const bf16* xb = xpT + (size_t)b * PADL * 512;

    const int lrow = lane >> 2;
    const int lcol = (lane & 3) * 8;
    const int wm = (wave & 1) * 64, wn = (wave >> 1) * 64;
    const int fr = lane & 15, quad = lane >> 4;

    floatx4 acc[4][4];
    #pragma unroll
    for (int i = 0; i < 4; i++)
        #pragma unroll
        for (int j = 0; j < 4; j++) acc[i][j] = (floatx4){0.f, 0.f, 0.f, 0.f};

    for (int k0 = 0; k0 < 512; k0 += 32) {
        for (int ga = wave; ga < 24; ga += 4) {
            int tap = ga >> 3, rg = ga & 7;
            gl_lds16(Wc + (size_t)tap * 262144 + (size_t)(m0 + rg * 16 + lrow) * 512 + k0 + lcol,
                     &As[ga * 512]);
        }
        for (int gb = wave; gb < 9; gb += 4) {
            gl_lds16(xb + (size_t)(n0 + gb * 16 + lrow) * 512 + k0 + lcol, &Bs[gb * 512]);
        }
        __syncthreads();
        #pragma unroll
        for (int tap = 0; tap < 3; tap++) {
            short8 af[4], bfv[4];
            #pragma unroll
            for (int i = 0; i < 4; i++)
                af[i] = *(const short8*)&As[tap * 4096 + (wm + i * 16 + fr) * 32 + quad * 8];
            #pragma unroll
            for (int j = 0; j < 4; j++)
                bfv[j] = *(const short8*)&Bs[(wn + j * 16 + fr + tap) * 32 + quad * 8];
            #pragma unroll
            for (int i = 0; i < 4; i++)
                #pragma unroll
                for (int j = 0; j < 4; j++)
                    acc[i][j] = __builtin_amdgcn_mfma_f32_16x16x32_bf16(af[i], bfv[j], acc[i][j], 0, 0, 0);
        }
        __syncthreads();
    }
    bf16* ob = Out + (size_t)b * CF * CT2;
    #pragma unroll
    for (int i = 0; i < 4; i++) {
        int mb = m0 + wm + i * 16 + quad * 4;
        #pragma unroll
        for (int r = 0; r < 4; r++) {
            float bv = bias[mb + r];
            #pragma unroll
            for (int j = 0; j < 4; j++) {
                int n = n0 + wn + j * 16 + fr;
                ob[(size_t)(mb + r) * CT2 + n] = f2b(silu_f(acc[i][j][r] + bv));
            }
        }
    }
}

// ---- out-GEMM (K=512, N=256 full width) with FUSED rmsnorm epilogue ----
__global__ __launch_bounds__(256) void gemm_rms_kernel(const bf16* __restrict__ A,
                                                       const bf16* __restrict__ Wt,
                                                       const float* __restrict__ bias,
                                                       const float* __restrict__ nw,
                                                       bf16* __restrict__ Xo,
                                                       bf16* __restrict__ XNo) {
    __shared__ __align__(16) short As[64 * 32];
    __shared__ __align__(16) short Bs[256 * 32];
    __shared__ float red[4][64];
    __shared__ float scl[64];
    const int tid = threadIdx.x;
    const int lane = tid & 63;
    const int wave = tid >> 6;
    const int m0 = blockIdx.x * 64;

    const int lrow = lane >> 2;
    const int lcol = (lane & 3) * 8;
    const bf16* aP = A + (size_t)(m0 + wave * 16 + lrow) * 512 + lcol;
    short* aL = &As[wave * 16 * 32];
    const bf16* bP[4];
    short* bL[4];
    #pragma unroll
    for (int g = 0; g < 4; g++) {
        int r0 = (wave * 4 + g) * 16;
        bP[g] = Wt + (size_t)(r0 + lrow) * 512 + lcol;
        bL[g] = &Bs[r0 * 32];
    }
    const int wn = wave * 64;
    const int fr = lane & 15, quad = lane >> 4;

    floatx4 acc[4][4];
    #pragma unroll
    for (int i = 0; i < 4; i++)
        #pragma unroll
        for (int j = 0; j < 4; j++) acc[i][j] = (floatx4){0.f, 0.f, 0.f, 0.f};

    for (int k0 = 0; k0 < 512; k0 += 32) {
        gl_lds16(aP + k0, aL);
        #pragma unroll
        for (int g = 0; g < 4; g++) gl_lds16(bP[g] + k0, bL[g]);
        __syncthreads();
        short8 af[4], bfv[4];
        #pragma unroll
        for (int i = 0; i < 4; i++) af[i] = *(const short8*)&As[(i * 16 + fr) * 32 + quad * 8];
        #pragma unroll
        for (int j = 0; j < 4; j++) bfv[j] = *(const short8*)&Bs[(wn + j * 16 + fr) * 32 + quad * 8];
        #pragma unroll
        for (int i = 0; i < 4; i++)
            #pragma unroll
            for (int j = 0; j < 4; j++)
                acc[i][j] = __builtin_amdgcn_mfma_f32_16x16x32_bf16(af[i], bfv[j], acc[i][j], 0, 0, 0);
        __syncthreads();
    }
    #pragma unroll
    for (int j = 0; j < 4; j++) {
        float bv = bias[wn + j * 16 + fr];
        #pragma unroll
        for (int i = 0; i < 4; i++)
            #pragma unroll
            for (int r = 0; r < 4; r++) acc[i][j][r] += bv;
    }
    #pragma unroll
    for (int i = 0; i < 4; i++) {
        #pragma unroll
        for (int r = 0; r < 4; r++) {
            float s = 0.f;
            #pragma unroll
            for (int j = 0; j < 4; j++) s += acc[i][j][r] * acc[i][j][r];
            #pragma unroll
            for (int o = 8; o > 0; o >>= 1) s += __shfl_xor(s, o);
            if (fr == 0) red[wave][i * 16 + quad * 4 + r] = s;
        }
    }
    __syncthreads();
    if (tid < 64) {
        float tot = red[0][tid] + red[1][tid] + red[2][tid] + red[3][tid];
        scl[tid] = rsqrtf(tot * (1.0f / CT) + 1e-5f);
    }
    __syncthreads();
    #pragma unroll
    for (int j = 0; j < 4; j++) {
        int n = wn + j * 16 + fr;
        float w = nw[n];
        #pragma unroll
        for (int i = 0; i < 4; i++) {
            int rl = i * 16 + quad * 4;
            #pragma unroll
            for (int r = 0; r < 4; r++) {
                float v = acc[i][j][r];
                Xo[(size_t)(m0 + rl + r) * CT + n] = f2b(v);
                XNo[(size_t)(m0 + rl + r) * CT + n] = f2b(v * scl[rl + r] * w);
            }
        }
    }
}

// ---- proj GEMM (K=256, N=256) with fused de-norm + transpose to fp32 out ----
__global__ __launch_bounds__(256) void proj_out_kernel(const bf16* __restrict__ A,
                                                       const bf16* __restrict__ Wt,
                                                       const float* __restrict__ bias,
                                                       const float* __restrict__ means,
                                                       const float* __restrict__ stdev,
                                                       float* __restrict__ out) {
    __shared__ __align__(16) short As[128 * 32];
    __shared__ __align__(16) short Bs[128 * 32];
    const int tid = threadIdx.x;
    const int lane = tid & 63;
    const int wave = tid >> 6;
    const int m0 = blockIdx.x * 128, n0 = blockIdx.y * 128;

    const int srow0 = wave * 32;
    const int lrow = lane >> 2;
    const int lcol = (lane & 3) * 8;
    const bf16* aP0 = A + (size_t)(m0 + srow0 + lrow) * 256 + lcol;
    const bf16* aP1 = A + (size_t)(m0 + srow0 + 16 + lrow) * 256 + lcol;
    const bf16* bP0 = Wt + (size_t)(n0 + srow0 + lrow) * 256 + lcol;
    const bf16* bP1 = Wt + (size_t)(n0 + srow0 + 16 + lrow) * 256 + lcol;
    short* aL0 = &As[srow0 * 32];
    short* aL1 = &As[(srow0 + 16) * 32];
    short* bL0 = &Bs[srow0 * 32];
    short* bL1 = &Bs[(srow0 + 16) * 32];

    const int wm = (wave & 1) * 64, wn = (wave >> 1) * 64;
    const int fr = lane & 15, quad = lane >> 4;

    floatx4 acc[4][4];
    #pragma unroll
    for (int i = 0; i < 4; i++)
        #pragma unroll
        for (int j = 0; j < 4; j++) acc[i][j] = (floatx4){0.f, 0.f, 0.f, 0.f};

    for (int k0 = 0; k0 < 256; k0 += 32) {
        gl_lds16(aP0 + k0, aL0);
        gl_lds16(aP1 + k0, aL1);
        gl_lds16(bP0 + k0, bL0);
        gl_lds16(bP1 + k0, bL1);
        __syncthreads();
        short8 af[4], bfv[4];
        #pragma unroll
        for (int i = 0; i < 4; i++) af[i] = *(const short8*)&As[(wm + i * 16 + fr) * 32 + quad * 8];
        #pragma unroll
        for (int j = 0; j < 4; j++) bfv[j] = *(const short8*)&Bs[(wn + j * 16 + fr) * 32 + quad * 8];
        #pragma unroll
        for (int i = 0; i < 4; i++)
            #pragma unroll
            for (int j = 0; j < 4; j++)
                acc[i][j] = __builtin_amdgcn_mfma_f32_16x16x32_bf16(af[i], bfv[j], acc[i][j], 0, 0, 0);
        __syncthreads();
    }
    #pragma unroll
    for (int j = 0; j < 4; j++) {
        int t = n0 + wn + j * 16 + fr;
        float bv = bias[t];
        #pragma unroll
        for (int i = 0; i < 4; i++) {
            int mb = m0 + wm + i * 16 + quad * 4;
            int b = mb >> 9;
            int nv = mb & 511;
            if (nv < CN) {
                floatx4 o;
                #pragma unroll
                for (int r = 0; r < 4; r++) {
                    int sn = b * CN + nv + r;
                    o[r] = (acc[i][j][r] + bv) * stdev[sn] + means[sn];
                }
                *(floatx4*)(out + ((size_t)(b * CT + t)) * CN + nv) = o;
            }
        }
    }
}

extern "C" void kernel_launch(void* const* d_in, const int* in_sizes, int n_in,
                              void* d_out, int out_size, void* d_ws, size_t ws_size,
                              hipStream_t stream) {
    const float* x_enc  = (const float*)d_in[0];
    const float* x_mark = (const float*)d_in[1];
    const float* norm_w = (const float*)d_in[4];
    const float* inp_W  = (const float*)d_in[5];
    const float* inp_b  = (const float*)d_in[6];
    const float* conv_W = (const float*)d_in[7];
    const float* conv_b = (const float*)d_in[8];
    const float* convlin_W = (const float*)d_in[9];
    const float* convlin_b = (const float*)d_in[10];
    const float* fc1_W = (const float*)d_in[11];
    const float* fc1_b = (const float*)d_in[12];
    const float* fc2_W = (const float*)d_in[13];
    const float* fc2_b = (const float*)d_in[14];
    const float* fc3_W = (const float*)d_in[15];
    const float* fc3_b = (const float*)d_in[16];
    const float* D_W   = (const float*)d_in[17];
    const float* D_b   = (const float*)d_in[18];
    const float* out_W = (const float*)d_in[19];
    const float* out_b = (const float*)d_in[20];
    const float* proj_W = (const float*)d_in[21];
    const float* proj_b = (const float*)d_in[22];

    // ---- workspace layout (~92 MB) ----
    char* ws = (char*)d_ws;
    float* MEANS = (float*)(ws);
    float* STDEV = (float*)(ws + 65536);
    float* CBv   = (float*)(ws + 131072);
    bf16* wt = (bf16*)(ws + 196608);
    bf16* wt_g1      = wt;                   // 3 x [1024][256]  (inp^T | D^T)
    bf16* wt_g3      = wt + 786432;          // 3 x [fc1^T 512x512 | fc2⊕fc3 512x512]
    bf16* wt_convlin = wt + 2359296;         // 3 x [512][512]
    bf16* wt_out     = wt + 3145728;         // 3 x [256][512]
    bf16* wt_proj    = wt + 3538944;         // [256][256]
    bf16* wt_conv    = wt + 3604480;         // 3 x [3][512][512]
    bf16* xpT = (bf16*)(ws + 12124160);      // [32][528][512] = 17.3 MB
    const size_t POOLB = 16777216;
    const size_t HALF = 16384 * 256;
    bf16* pool[4] = {
        (bf16*)(ws + 29425664),
        (bf16*)(ws + 29425664 + POOLB),
        (bf16*)(ws + 29425664 + 2 * POOLB),
        (bf16*)(ws + 29425664 + 3 * POOLB),
    };
    float* out = (float*)d_out;

    // ---- prepack ----
    P8 p;
    p.s[0] = inp_W;  p.d[0] = wt_g1;
    p.s[1] = D_W;    p.d[1] = wt_g1 + 131072;
    p.s[2] = fc1_W;  p.d[2] = wt_g3;
    p.s[3] = fc2_W;  p.d[3] = wt_g3 + 262144;   // interleaved rows 2c
    p.s[4] = fc3_W;  p.d[4] = wt_g3 + 262144;   // interleaved rows 2c+1
    p.s[5] = convlin_W; p.d[5] = wt_convlin;
    p.s[6] = out_W;  p.d[6] = wt_out;
    p.s[7] = proj_W; p.d[7] = wt_proj;
    prepack_all_kernel<<<3520, 256, 0, stream>>>(p);
    convpack_kernel<<<(CONVN + 32768 + MROWS + 255) / 256, 256, 0, stream>>>(
        conv_W, wt_conv, xpT, CBv);

    // ---- fused stats + build + rmsnorm(iter0): xn -> pool[0].hi ----
    buildx_rms_kernel<<<256, 256, 0, stream>>>(x_enc, x_mark, norm_w, MEANS, STDEV,
                                               pool[0] + HALF);

    // 4-pool rotation
    int ia = 0, ico = 1, ires = 2, iout = 3;
    for (int i = 0; i < 3; i++) {
        bf16* A  = pool[ia];
        bf16* XCO = pool[ico];
        bf16* XRES = pool[ires];
        bf16* OUTP = pool[iout];
        bf16* XN = A + HALF;

        // [xp|xres] = xn @ [inp|D] + b : xp -> xpT (transposed), xres -> XRES
        mgemm_kernel<1><<<dim3(128, 8), 256, 0, stream>>>(
            XN, wt_g1 + (size_t)i * 262144, inp_b + i * CT2, D_b + i * CT2,
            xpT, XRES, 256, 1024);
        // xc = silu(conv(xp)) -> A ; also zeroes CBv for cbgemm below
        conv_mfma_kernel<<<512, 256, 0, stream>>>(wt_conv + (size_t)i * 786432, xpT,
                                                  conv_b + i * CF, A, CBv);
        // xco = xc @ convlin + b -> XCO
        mgemm_kernel<0><<<dim3(128, 4), 256, 0, stream>>>(
            A, wt_convlin + (size_t)i * 262144, convlin_b + i * CT2, nullptr,
            XCO, nullptr, 512, 512);
        // cb[row] += (xco@fc2+b2)·(xco@fc3+b3) via interleaved GEMM + atomics
        cbgemm_kernel<<<dim3(128, 4), 256, 0, stream>>>(
            XCO, wt_g3 + (size_t)i * 524288 + 262144, fc2_b + i * CT, fc3_b + i * CT, CBv);
        // g = silu(softplus(xco@fc1+b1)*xco*cb)*xres -> A (fused gate epilogue)
        fc1gate_kernel<<<dim3(128, 4), 256, 0, stream>>>(
            XCO, wt_g3 + (size_t)i * 524288, fc1_b + i * CT2, CBv, XRES, A);
        // x_next = g @ out_W + b -> OUTP.lo ; rmsnorm -> OUTP.hi
        gemm_rms_kernel<<<256, 256, 0, stream>>>(
            A, wt_out + (size_t)i * 131072, out_b + i * CT,
            norm_w + ((i + 1) % 3) * CT, OUTP, OUTP + HALF);

        int na = iout, nco = ia, nres = ico, nout = ires;
        ia = na; ico = nco; ires = nres; iout = nout;
    }

    // x_final in pool[ia] (lo). dec = x @ proj_W + b, de-norm + transpose to out
    proj_out_kernel<<<dim3(128, 2), 256, 0, stream>>>(
        pool[ia], wt_proj, proj_b, MEANS, STDEV, out);
}

// Round 11
// 556.066 us; speedup vs baseline: 1.2067x; 1.0248x over previous
//
#include <hip/hip_runtime.h>
#include <hip/hip_bf16.h>
#include <math.h>

typedef __hip_bfloat16 bf16;
typedef short short8 __attribute__((ext_vector_type(8)));
typedef short short4v __attribute__((ext_vector_type(4)));
typedef float floatx4 __attribute__((ext_vector_type(4)));

constexpr int CB_ = 32;
constexpr int CT = 256;
constexpr int CF = 512;
constexpr int CN = 508;
constexpr int CM = 4;
constexpr int CT2 = 512;
constexpr int MROWS = CB_ * CF;  // 16384
constexpr int PADL = 528;

__device__ __forceinline__ float b2f(bf16 v) { return __bfloat162float(v); }
__device__ __forceinline__ bf16 f2b(float v) { return __float2bfloat16(v); }
__device__ __forceinline__ float s2f(short s) {
    unsigned u = ((unsigned)(unsigned short)s) << 16;
    return __builtin_bit_cast(float, u);
}
__device__ __forceinline__ short f2s(float v) {
    bf16 t = __float2bfloat16(v);
    return __builtin_bit_cast(short, t);
}
__device__ __forceinline__ float silu_f(float x) { return x / (1.0f + __expf(-x)); }
__device__ __forceinline__ float softplus_f(float x) {
    return fmaxf(x, 0.0f) + __logf(1.0f + __expf(-fabsf(x)));
}

__device__ __forceinline__ void gl_lds16(const bf16* g, short* l) {
    __builtin_amdgcn_global_load_lds(
        (const __attribute__((address_space(1))) unsigned int*)(g),
        (__attribute__((address_space(3))) unsigned int*)(l), 16, 0, 0);
}

// ---- ALL prepack in one kernel: 8 weight transposes (+nw folding for inp/D),
// conv weight pack, xpT pad rows, CBv zero.
// fc2/fc3 interleaved: dst row = 2c (fc2) / 2c+1 (fc3). inp/D get nw_i folded
// into their K-rows so rmsnorm scale can be applied per-row in the GEMM epilogue.
constexpr int CONVN = 3 * 3 * 512 * 512;  // 2359296
constexpr int MTILES = 3520;
struct P8 { const float* s[8]; bf16* d[8]; };
__global__ __launch_bounds__(256) void prepack_all_kernel(P8 p, const float* __restrict__ nw,
                                                          const float* __restrict__ convW,
                                                          bf16* __restrict__ convD,
                                                          bf16* __restrict__ xpT,
                                                          float* __restrict__ CBv) {
    int bid = blockIdx.x;
    if (bid >= MTILES) {
        int idx = (bid - MTILES) * 256 + threadIdx.x;
        if (idx < CONVN) {
            int ci = idx & 511;
            int co = (idx >> 9) & 511;
            int it = idx >> 18;
            int tap = it % 3, ib = it / 3;
            convD[idx] = f2b(convW[(((size_t)(ib * 512 + co)) * 512 + ci) * 3 + tap]);
        } else if (idx < CONVN + 32768) {
            int j = idx - CONVN;
            int ci = j & 511;
            int w = (j >> 9) & 1;
            int b = j >> 10;
            xpT[((size_t)b * PADL + (w ? 513 : 0)) * 512 + ci] = f2b(0.0f);
        } else if (idx < CONVN + 32768 + MROWS) {
            CBv[idx - CONVN - 32768] = 0.0f;
        }
        return;
    }
    const int Ks[8]   = {256, 256, 512, 512, 512, 512, 512, 256};
    const int Ns[8]   = {512, 512, 512, 256, 256, 512, 256, 256};
    const int zs[8]   = {3, 3, 3, 3, 3, 3, 3, 1};
    const int dstr[8] = {262144, 262144, 524288, 524288, 524288, 262144, 131072, 65536};
    const int rml[8]  = {1, 1, 1, 2, 2, 1, 1, 1};
    const int rad[8]  = {0, 0, 0, 0, 1, 0, 0, 0};
    int m = 0, acc = 0;
    for (m = 0; m < 8; m++) {
        int c = (Ns[m] >> 5) * (Ks[m] >> 5) * zs[m];
        if (bid < acc + c) break;
        acc += c;
    }
    int lid = bid - acc;
    int K = Ks[m], N = Ns[m];
    int tx = N >> 5, ty = K >> 5;
    int z = lid / (tx * ty), rem = lid % (tx * ty);
    int k0 = (rem / tx) * 32, n0 = (rem % tx) * 32;
    const float* s = p.s[m] + (size_t)z * K * N;
    bf16* d = p.d[m] + (size_t)z * dstr[m];
    int mul = rml[m], add = rad[m];
    bool fold = (m <= 1);  // inp_W, D_W: fold nw_z into K-rows
    __shared__ float Ts[32][33];
    for (int e = threadIdx.x; e < 1024; e += 256) {
        int r = e >> 5, c = e & 31;
        float v = s[(size_t)(k0 + r) * N + n0 + c];
        if (fold) v *= nw[z * 256 + k0 + r];
        Ts[r][c] = v;
    }
    __syncthreads();
    for (int e = threadIdx.x; e < 1024; e += 256) {
        int r = e >> 5, c = e & 31;
        d[(size_t)((n0 + r) * mul + add) * K + k0 + c] = f2b(Ts[c][r]);
    }
}

// ---- fused stats + build_x (iter 0): writes RAW x (bf16) + rms scale SCL ----
__global__ __launch_bounds__(256) void buildx_kernel(
    const float* __restrict__ xe, const float* __restrict__ xm,
    float* __restrict__ means, float* __restrict__ stdev,
    bf16* __restrict__ X0, float* __restrict__ SCL) {
    __shared__ float L[256][65];
    __shared__ float red_s[4][64], red_q[4][64];
    __shared__ float stat_m[64], stat_i[64];
    int blk = blockIdx.x;
    int b = blk >> 3, f0 = (blk & 7) * 64;
    int tid = threadIdx.x;
    int j = tid & 63, tq = tid >> 6;
    int f = f0 + j;
    float ps = 0.f, pq = 0.f;
    const float* xep = xe + (size_t)b * CT * CN + f;
    const float* xmp = xm + (size_t)b * CT * CM + (f - CN);
    #pragma unroll 4
    for (int tt = 0; tt < 64; tt++) {
        int t = tq * 64 + tt;
        float v = (f < CN) ? xep[(size_t)t * CN] : xmp[(size_t)t * CM];
        L[t][j] = v;
        ps += v;
        pq += v * v;
    }
    red_s[tq][j] = ps;
    red_q[tq][j] = pq;
    __syncthreads();
    if (tid < 64) {
        int ff = f0 + tid;
        float s = red_s[0][tid] + red_s[1][tid] + red_s[2][tid] + red_s[3][tid];
        float q = red_q[0][tid] + red_q[1][tid] + red_q[2][tid] + red_q[3][tid];
        float mean, isd, msq;
        if (ff < CN) {
            mean = s * (1.0f / 256.0f);
            float var = fmaxf(q * (1.0f / 256.0f) - mean * mean, 0.0f);
            float sd = sqrtf(var + 1e-5f);
            isd = 1.0f / sd;
            means[b * CN + ff] = mean;
            stdev[b * CN + ff] = sd;
            msq = var / (var + 1e-5f);
        } else {
            mean = 0.0f;
            isd = 1.0f;
            msq = q * (1.0f / 256.0f);
        }
        stat_m[tid] = mean;
        stat_i[tid] = isd;
        SCL[b * 512 + ff] = rsqrtf(msq + 1e-5f);
    }
    __syncthreads();
    bf16* outp = X0 + ((size_t)(b * 512 + f0)) * 256;
    int t = tid;
    #pragma unroll 4
    for (int fp = 0; fp < 64; fp++) {
        float val = (L[t][fp] - stat_m[fp]) * stat_i[fp];
        outp[(size_t)fp * 256 + t] = f2b(val);
    }
}

// ---- MFMA GEMM (m97 structure). MODE 0: plain.
// MODE 1: [inp|D] with per-row SCL applied in epilogue (nw pre-folded into W). ----
template <int MODE>
__global__ __launch_bounds__(256) void mgemm_kernel(const bf16* __restrict__ A,
                                                    const bf16* __restrict__ Wt,
                                                    const float* __restrict__ b1,
                                                    const float* __restrict__ b2,
                                                    const float* __restrict__ SCL,
                                                    bf16* __restrict__ o1,
                                                    bf16* __restrict__ o2,
                                                    int K, int Ncols) {
    __shared__ __align__(16) short As[128 * 32];
    __shared__ __align__(16) short Bs[128 * 32];
    const int tid = threadIdx.x;
    const int lane = tid & 63;
    const int wave = tid >> 6;
    const int m0 = blockIdx.x * 128, n0 = blockIdx.y * 128;

    const int srow0 = wave * 32;
    const int lrow = lane >> 2;
    const int lcol = (lane & 3) * 8;

    const bf16* aP0 = A + (size_t)(m0 + srow0 + lrow) * K + lcol;
    const bf16* aP1 = A + (size_t)(m0 + srow0 + 16 + lrow) * K + lcol;
    const bf16* bP0 = Wt + (size_t)(n0 + srow0 + lrow) * K + lcol;
    const bf16* bP1 = Wt + (size_t)(n0 + srow0 + 16 + lrow) * K + lcol;
    short* aL0 = &As[srow0 * 32];
    short* aL1 = &As[(srow0 + 16) * 32];
    short* bL0 = &Bs[srow0 * 32];
    short* bL1 = &Bs[(srow0 + 16) * 32];

    const int wm = (wave & 1) * 64, wn = (wave >> 1) * 64;
    const int fr = lane & 15, quad = lane >> 4;

    floatx4 acc[4][4];
    #pragma unroll
    for (int i = 0; i < 4; i++)
        #pragma unroll
        for (int j = 0; j < 4; j++) acc[i][j] = (floatx4){0.f, 0.f, 0.f, 0.f};

    for (int k0 = 0; k0 < K; k0 += 32) {
        gl_lds16(aP0 + k0, aL0);
        gl_lds16(aP1 + k0, aL1);
        gl_lds16(bP0 + k0, bL0);
        gl_lds16(bP1 + k0, bL1);
        __syncthreads();
        short8 af[4], bfv[4];
        #pragma unroll
        for (int i = 0; i < 4; i++) af[i] = *(const short8*)&As[(wm + i * 16 + fr) * 32 + quad * 8];
        #pragma unroll
        for (int j = 0; j < 4; j++) bfv[j] = *(const short8*)&Bs[(wn + j * 16 + fr) * 32 + quad * 8];
        #pragma unroll
        for (int i = 0; i < 4; i++)
            #pragma unroll
            for (int j = 0; j < 4; j++)
                acc[i][j] = __builtin_amdgcn_mfma_f32_16x16x32_bf16(af[i], bfv[j], acc[i][j], 0, 0, 0);
        __syncthreads();
    }

    if (MODE == 0) {
        #pragma unroll
        for (int j = 0; j < 4; j++) {
            int n = n0 + wn + j * 16 + fr;
            float bv = b1[n];
            #pragma unroll
            for (int i = 0; i < 4; i++) {
                int mb = m0 + wm + i * 16 + quad * 4;
                #pragma unroll
                for (int r = 0; r < 4; r++)
                    o1[(size_t)(mb + r) * Ncols + n] = f2b(acc[i][j][r] + bv);
            }
        }
    } else {  // MODE 1: [inp|D] with per-row rms scale
        if (n0 + wn < 512) {
            int b = (m0 + wm) >> 9;
            #pragma unroll
            for (int i = 0; i < 4; i++) {
                int mb = m0 + wm + i * 16 + quad * 4;
                float sclr[4];
                #pragma unroll
                for (int r = 0; r < 4; r++) sclr[r] = SCL[mb + r];
                #pragma unroll
                for (int j = 0; j < 4; j++) {
                    int n = n0 + wn + j * 16 + fr;
                    float bv = b1[n];
                    bf16* dst = o1 + ((size_t)b * PADL + n + 1) * 512;
                    int ci = mb & 511;
                    short4v pk;
                    #pragma unroll
                    for (int r = 0; r < 4; r++) pk[r] = f2s(acc[i][j][r] * sclr[r] + bv);
                    *(short4v*)(dst + ci) = pk;
                }
            }
        } else {
            #pragma unroll
            for (int i = 0; i < 4; i++) {
                int mb = m0 + wm + i * 16 + quad * 4;
                float sclr[4];
                #pragma unroll
                for (int r = 0; r < 4; r++) sclr[r] = SCL[mb + r];
                #pragma unroll
                for (int j = 0; j < 4; j++) {
                    int n = n0 + wn + j * 16 + fr;
                    float bv = b2[n - 512];
                    #pragma unroll
                    for (int r = 0; r < 4; r++)
                        o2[(size_t)(mb + r) * 512 + (n - 512)] =
                            f2b(silu_f(acc[i][j][r] * sclr[r] + bv));
                }
            }
        }
    }
}

// ---- cb GEMM: xco @ [fc2⊕fc3 interleaved], epilogue = cb atomics only ----
__global__ __launch_bounds__(256) void cbgemm_kernel(const bf16* __restrict__ A,
                                                     const bf16* __restrict__ Wt,
                                                     const float* __restrict__ b2,
                                                     const float* __restrict__ b3,
                                                     float* __restrict__ CBv) {
    __shared__ __align__(16) short As[128 * 32];
    __shared__ __align__(16) short Bs[128 * 32];
    const int tid = threadIdx.x;
    const int lane = tid & 63;
    const int wave = tid >> 6;
    const int m0 = blockIdx.x * 128, n0 = blockIdx.y * 128;

    const int srow0 = wave * 32;
    const int lrow = lane >> 2;
    const int lcol = (lane & 3) * 8;
    const bf16* aP0 = A + (size_t)(m0 + srow0 + lrow) * 512 + lcol;
    const bf16* aP1 = A + (size_t)(m0 + srow0 + 16 + lrow) * 512 + lcol;
    const bf16* bP0 = Wt + (size_t)(n0 + srow0 + lrow) * 512 + lcol;
    const bf16* bP1 = Wt + (size_t)(n0 + srow0 + 16 + lrow) * 512 + lcol;
    short* aL0 = &As[srow0 * 32];
    short* aL1 = &As[(srow0 + 16) * 32];
    short* bL0 = &Bs[srow0 * 32];
    short* bL1 = &Bs[(srow0 + 16) * 32];

    const int wm = (wave & 1) * 64, wn = (wave >> 1) * 64;
    const int fr = lane & 15, quad = lane >> 4;

    floatx4 acc[4][4];
    #pragma unroll
    for (int i = 0; i < 4; i++)
        #pragma unroll
        for (int j = 0; j < 4; j++) acc[i][j] = (floatx4){0.f, 0.f, 0.f, 0.f};

    for (int k0 = 0; k0 < 512; k0 += 32) {
        gl_lds16(aP0 + k0, aL0);
        gl_lds16(aP1 + k0, aL1);
        gl_lds16(bP0 + k0, bL0);
        gl_lds16(bP1 + k0, bL1);
        __syncthreads();
        short8 af[4], bfv[4];
        #pragma unroll
        for (int i = 0; i < 4; i++) af[i] = *(const short8*)&As[(wm + i * 16 + fr) * 32 + quad * 8];
        #pragma unroll
        for (int j = 0; j < 4; j++) bfv[j] = *(const short8*)&Bs[(wn + j * 16 + fr) * 32 + quad * 8];
        #pragma unroll
        for (int i = 0; i < 4; i++)
            #pragma unroll
            for (int j = 0; j < 4; j++)
                acc[i][j] = __builtin_amdgcn_mfma_f32_16x16x32_bf16(af[i], bfv[j], acc[i][j], 0, 0, 0);
        __syncthreads();
    }
    int nnb = n0 + wn;
    float bv[4];
    #pragma unroll
    for (int j = 0; j < 4; j++) {
        int nn = nnb + j * 16 + fr;
        int c = nn >> 1;
        bv[j] = (fr & 1) ? b3[c] : b2[c];
    }
    #pragma unroll
    for (int i = 0; i < 4; i++) {
        #pragma unroll
        for (int r = 0; r < 4; r++) {
            float s = 0.f;
            #pragma unroll
            for (int j = 0; j < 4; j++) {
                float v = acc[i][j][r] + bv[j];
                s += v * __shfl_xor(v, 1);
            }
            s += __shfl_xor(s, 2);
            s += __shfl_xor(s, 4);
            s += __shfl_xor(s, 8);
            if (fr == 0)
                atomicAdd(&CBv[m0 + wm + i * 16 + quad * 4 + r], s * 0.5f);
        }
    }
}

// ---- fc1 GEMM with FUSED s6 gate epilogue ----
__global__ __launch_bounds__(256) void fc1gate_kernel(const bf16* __restrict__ A,
                                                      const bf16* __restrict__ Wt,
                                                      const float* __restrict__ b1,
                                                      const float* __restrict__ CBv,
                                                      const bf16* __restrict__ Xres,
                                                      bf16* __restrict__ G) {
    __shared__ __align__(16) short As[128 * 32];
    __shared__ __align__(16) short Bs[128 * 32];
    const int tid = threadIdx.x;
    const int lane = tid & 63;
    const int wave = tid >> 6;
    const int m0 = blockIdx.x * 128, n0 = blockIdx.y * 128;

    const int srow0 = wave * 32;
    const int lrow = lane >> 2;
    const int lcol = (lane & 3) * 8;
    const bf16* aP0 = A + (size_t)(m0 + srow0 + lrow) * 512 + lcol;
    const bf16* aP1 = A + (size_t)(m0 + srow0 + 16 + lrow) * 512 + lcol;
    const bf16* bP0 = Wt + (size_t)(n0 + srow0 + lrow) * 512 + lcol;
    const bf16* bP1 = Wt + (size_t)(n0 + srow0 + 16 + lrow) * 512 + lcol;
    short* aL0 = &As[srow0 * 32];
    short* aL1 = &As[(srow0 + 16) * 32];
    short* bL0 = &Bs[srow0 * 32];
    short* bL1 = &Bs[(srow0 + 16) * 32];

    const int wm = (wave & 1) * 64, wn = (wave >> 1) * 64;
    const int fr = lane & 15, quad = lane >> 4;

    floatx4 acc[4][4];
    #pragma unroll
    for (int i = 0; i < 4; i++)
        #pragma unroll
        for (int j = 0; j < 4; j++) acc[i][j] = (floatx4){0.f, 0.f, 0.f, 0.f};

    for (int k0 = 0; k0 < 512; k0 += 32) {
        gl_lds16(aP0 + k0, aL0);
        gl_lds16(aP1 + k0, aL1);
        gl_lds16(bP0 + k0, bL0);
        gl_lds16(bP1 + k0, bL1);
        __syncthreads();
        short8 af[4], bfv[4];
        #pragma unroll
        for (int i = 0; i < 4; i++) af[i] = *(const short8*)&As[(wm + i * 16 + fr) * 32 + quad * 8];
        #pragma unroll
        for (int j = 0; j < 4; j++) bfv[j] = *(const short8*)&Bs[(wn + j * 16 + fr) * 32 + quad * 8];
        #pragma unroll
        for (int i = 0; i < 4; i++)
            #pragma unroll
            for (int j = 0; j < 4; j++)
                acc[i][j] = __builtin_amdgcn_mfma_f32_16x16x32_bf16(af[i], bfv[j], acc[i][j], 0, 0, 0);
        __syncthreads();
    }
    #pragma unroll
    for (int i = 0; i < 4; i++) {
        int mb = m0 + wm + i * 16 + quad * 4;
        float cbr[4];
        #pragma unroll
        for (int r = 0; r < 4; r++) cbr[r] = CBv[mb + r];
        #pragma unroll
        for (int j = 0; j < 4; j++) {
            int n = n0 + wn + j * 16 + fr;
            float bv = b1[n];
            #pragma unroll
            for (int r = 0; r < 4; r++) {
                size_t off = (size_t)(mb + r) * 512 + n;
                float delta = softplus_f(acc[i][j][r] + bv);
                float xssm = delta * b2f(A[off]) * cbr[r];
                G[off] = f2b(silu_f(xssm) * b2f(Xres[off]));
            }
        }
    }
}

// ---- conv as implicit MFMA GEMM + CBv zeroing at entry ----
__global__ __launch_bounds__(256) void conv_mfma_kernel(const bf16* __restrict__ Wc,
                                                        const bf16* __restrict__ xpT,
                                                        const float* __restrict__ bias,
                                                        bf16* __restrict__ Out,
                                                        float* __restrict__ CBvZ) {
    __shared__ __align__(16) short As[3 * 128 * 32];
    __shared__ __align__(16) short Bs[144 * 32];
    const int tid = threadIdx.x;
    const int lane = tid & 63;
    const int wave = tid >> 6;
    int bx = blockIdx.x;
    if (bx < 128 && tid < 128) CBvZ[bx * 128 + tid] = 0.0f;
    int xcd = bx & 7, g = bx >> 3;
    int mt = g & 3;
    int id = xcd * 16 + (g >> 2);
    int nt = id & 3, b = id >> 2;
    const int m0 = mt * 128, n0 = nt * 128;
    const bf16* xb = xpT + (size_t)b * PADL * 512;

    const int lrow = lane >> 2;
    const int lcol = (lane & 3) * 8;
    const int wm = (wave & 1) * 64, wn = (wave >> 1) * 64;
    const int fr = lane & 15, quad = lane >> 4;

    floatx4 acc[4][4];
    #pragma unroll
    for (int i = 0; i < 4; i++)
        #pragma unroll
        for (int j = 0; j < 4; j++) acc[i][j] = (floatx4){0.f, 0.f, 0.f, 0.f};

    for (int k0 = 0; k0 < 512; k0 += 32) {
        for (int ga = wave; ga < 24; ga += 4) {
            int tap = ga >> 3, rg = ga & 7;
            gl_lds16(Wc + (size_t)tap * 262144 + (size_t)(m0 + rg * 16 + lrow) * 512 + k0 + lcol,
                     &As[ga * 512]);
        }
        for (int gb = wave; gb < 9; gb += 4) {
            gl_lds16(xb + (size_t)(n0 + gb * 16 + lrow) * 512 + k0 + lcol, &Bs[gb * 512]);
        }
        __syncthreads();
        #pragma unroll
        for (int tap = 0; tap < 3; tap++) {
            short8 af[4], bfv[4];
            #pragma unroll
            for (int i = 0; i < 4; i++)
                af[i] = *(const short8*)&As[tap * 4096 + (wm + i * 16 + fr) * 32 + quad * 8];
            #pragma unroll
            for (int j = 0; j < 4; j++)
                bfv[j] = *(const short8*)&Bs[(wn + j * 16 + fr + tap) * 32 + quad * 8];
            #pragma unroll
            for (int i = 0; i < 4; i++)
                #pragma unroll
                for (int j = 0; j < 4; j++)
                    acc[i][j] = __builtin_amdgcn_mfma_f32_16x16x32_bf16(af[i], bfv[j], acc[i][j], 0, 0, 0);
        }
        __syncthreads();
    }
    bf16* ob = Out + (size_t)b * CF * CT2;
    #pragma unroll
    for (int i = 0; i < 4; i++) {
        int mb = m0 + wm + i * 16 + quad * 4;
        #pragma unroll
        for (int r = 0; r < 4; r++) {
            float bv = bias[mb + r];
            #pragma unroll
            for (int j = 0; j < 4; j++) {
                int n = n0 + wn + j * 16 + fr;
                ob[(size_t)(mb + r) * CT2 + n] = f2b(silu_f(acc[i][j][r] + bv));
            }
        }
    }
}

// ---- out-GEMM (K=512, N=256) + rms scale computation (NOT applied): writes
// x_next (bf16) + SCL[row] (fp32). nw application deferred to next GEMM (folded W).
__global__ __launch_bounds__(256) void gemm_scl_kernel(const bf16* __restrict__ A,
                                                       const bf16* __restrict__ Wt,
                                                       const float* __restrict__ bias,
                                                       bf16* __restrict__ Xo,
                                                       float* __restrict__ SCL) {
    __shared__ __align__(16) short As[64 * 32];
    __shared__ __align__(16) short Bs[256 * 32];
    __shared__ float red[4][64];
    const int tid = threadIdx.x;
    const int lane = tid & 63;
    const int wave = tid >> 6;
    const int m0 = blockIdx.x * 64;

    const int lrow = lane >> 2;
    const int lcol = (lane & 3) * 8;
    const bf16* aP = A + (size_t)(m0 + wave * 16 + lrow) * 512 + lcol;
    short* aL = &As[wave * 16 * 32];
    const bf16* bP[4];
    short* bL[4];
    #pragma unroll
    for (int g = 0; g < 4; g++) {
        int r0 = (wave * 4 + g) * 16;
        bP[g] = Wt + (size_t)(r0 + lrow) * 512 + lcol;
        bL[g] = &Bs[r0 * 32];
    }
    const int wn = wave * 64;
    const int fr = lane & 15, quad = lane >> 4;

    floatx4 acc[4][4];
    #pragma unroll
    for (int i = 0; i < 4; i++)
        #pragma unroll
        for (int j = 0; j < 4; j++) acc[i][j] = (floatx4){0.f, 0.f, 0.f, 0.f};

    for (int k0 = 0; k0 < 512; k0 += 32) {
        gl_lds16(aP + k0, aL);
        #pragma unroll
        for (int g = 0; g < 4; g++) gl_lds16(bP[g] + k0, bL[g]);
        __syncthreads();
        short8 af[4], bfv[4];
        #pragma unroll
        for (int i = 0; i < 4; i++) af[i] = *(const short8*)&As[(i * 16 + fr) * 32 + quad * 8];
        #pragma unroll
        for (int j = 0; j < 4; j++) bfv[j] = *(const short8*)&Bs[(wn + j * 16 + fr) * 32 + quad * 8];
        #pragma unroll
        for (int i = 0; i < 4; i++)
            #pragma unroll
            for (int j = 0; j < 4; j++)
                acc[i][j] = __builtin_amdgcn_mfma_f32_16x16x32_bf16(af[i], bfv[j], acc[i][j], 0, 0, 0);
        __syncthreads();
    }
    #pragma unroll
    for (int j = 0; j < 4; j++) {
        float bv = bias[wn + j * 16 + fr];
        #pragma unroll
        for (int i = 0; i < 4; i++)
            #pragma unroll
            for (int r = 0; r < 4; r++) acc[i][j][r] += bv;
    }
    #pragma unroll
    for (int i = 0; i < 4; i++) {
        #pragma unroll
        for (int r = 0; r < 4; r++) {
            float s = 0.f;
            #pragma unroll
            for (int j = 0; j < 4; j++) s += acc[i][j][r] * acc[i][j][r];
            #pragma unroll
            for (int o = 8; o > 0; o >>= 1) s += __shfl_xor(s, o);
            if (fr == 0) red[wave][i * 16 + quad * 4 + r] = s;
        }
    }
    __syncthreads();
    if (tid < 64) {
        float tot = red[0][tid] + red[1][tid] + red[2][tid] + red[3][tid];
        SCL[m0 + tid] = rsqrtf(tot * (1.0f / CT) + 1e-5f);
    }
    #pragma unroll
    for (int j = 0; j < 4; j++) {
        int n = wn + j * 16 + fr;
        #pragma unroll
        for (int i = 0; i < 4; i++) {
            int rl = i * 16 + quad * 4;
            #pragma unroll
            for (int r = 0; r < 4; r++)
                Xo[(size_t)(m0 + rl + r) * CT + n] = f2b(acc[i][j][r]);
        }
    }
}

// ---- proj GEMM (K=256, N=256) with fused de-norm + transpose to fp32 out ----
__global__ __launch_bounds__(256) void proj_out_kernel(const bf16* __restrict__ A,
                                                       const bf16* __restrict__ Wt,
                                                       const float* __restrict__ bias,
                                                       const float* __restrict__ means,
                                                       const float* __restrict__ stdev,
                                                       float* __restrict__ out) {
    __shared__ __align__(16) short As[128 * 32];
    __shared__ __align__(16) short Bs[128 * 32];
    const int tid = threadIdx.x;
    const int lane = tid & 63;
    const int wave = tid >> 6;
    const int m0 = blockIdx.x * 128, n0 = blockIdx.y * 128;

    const int srow0 = wave * 32;
    const int lrow = lane >> 2;
    const int lcol = (lane & 3) * 8;
    const bf16* aP0 = A + (size_t)(m0 + srow0 + lrow) * 256 + lcol;
    const bf16* aP1 = A + (size_t)(m0 + srow0 + 16 + lrow) * 256 + lcol;
    const bf16* bP0 = Wt + (size_t)(n0 + srow0 + lrow) * 256 + lcol;
    const bf16* bP1 = Wt + (size_t)(n0 + srow0 + 16 + lrow) * 256 + lcol;
    short* aL0 = &As[srow0 * 32];
    short* aL1 = &As[(srow0 + 16) * 32];
    short* bL0 = &Bs[srow0 * 32];
    short* bL1 = &Bs[(srow0 + 16) * 32];

    const int wm = (wave & 1) * 64, wn = (wave >> 1) * 64;
    const int fr = lane & 15, quad = lane >> 4;

    floatx4 acc[4][4];
    #pragma unroll
    for (int i = 0; i < 4; i++)
        #pragma unroll
        for (int j = 0; j < 4; j++) acc[i][j] = (floatx4){0.f, 0.f, 0.f, 0.f};

    for (int k0 = 0; k0 < 256; k0 += 32) {
        gl_lds16(aP0 + k0, aL0);
        gl_lds16(aP1 + k0, aL1);
        gl_lds16(bP0 + k0, bL0);
        gl_lds16(bP1 + k0, bL1);
        __syncthreads();
        short8 af[4], bfv[4];
        #pragma unroll
        for (int i = 0; i < 4; i++) af[i] = *(const short8*)&As[(wm + i * 16 + fr) * 32 + quad * 8];
        #pragma unroll
        for (int j = 0; j < 4; j++) bfv[j] = *(const short8*)&Bs[(wn + j * 16 + fr) * 32 + quad * 8];
        #pragma unroll
        for (int i = 0; i < 4; i++)
            #pragma unroll
            for (int j = 0; j < 4; j++)
                acc[i][j] = __builtin_amdgcn_mfma_f32_16x16x32_bf16(af[i], bfv[j], acc[i][j], 0, 0, 0);
        __syncthreads();
    }
    #pragma unroll
    for (int j = 0; j < 4; j++) {
        int t = n0 + wn + j * 16 + fr;
        float bv = bias[t];
        #pragma unroll
        for (int i = 0; i < 4; i++) {
            int mb = m0 + wm + i * 16 + quad * 4;
            int b = mb >> 9;
            int nv = mb & 511;
            if (nv < CN) {
                floatx4 o;
                #pragma unroll
                for (int r = 0; r < 4; r++) {
                    int sn = b * CN + nv + r;
                    o[r] = (acc[i][j][r] + bv) * stdev[sn] + means[sn];
                }
                *(floatx4*)(out + ((size_t)(b * CT + t)) * CN + nv) = o;
            }
        }
    }
}

extern "C" void kernel_launch(void* const* d_in, const int* in_sizes, int n_in,
                              void* d_out, int out_size, void* d_ws, size_t ws_size,
                              hipStream_t stream) {
    const float* x_enc  = (const float*)d_in[0];
    const float* x_mark = (const float*)d_in[1];
    const float* norm_w = (const float*)d_in[4];
    const float* inp_W  = (const float*)d_in[5];
    const float* inp_b  = (const float*)d_in[6];
    const float* conv_W = (const float*)d_in[7];
    const float* conv_b = (const float*)d_in[8];
    const float* convlin_W = (const float*)d_in[9];
    const float* convlin_b = (const float*)d_in[10];
    const float* fc1_W = (const float*)d_in[11];
    const float* fc1_b = (const float*)d_in[12];
    const float* fc2_W = (const float*)d_in[13];
    const float* fc2_b = (const float*)d_in[14];
    const float* fc3_W = (const float*)d_in[15];
    const float* fc3_b = (const float*)d_in[16];
    const float* D_W   = (const float*)d_in[17];
    const float* D_b   = (const float*)d_in[18];
    const float* out_W = (const float*)d_in[19];
    const float* out_b = (const float*)d_in[20];
    const float* proj_W = (const float*)d_in[21];
    const float* proj_b = (const float*)d_in[22];

    // ---- workspace layout ----
    char* ws = (char*)d_ws;
    float* MEANS = (float*)(ws);
    float* STDEV = (float*)(ws + 65536);
    float* CBv   = (float*)(ws + 131072);
    float* SCL   = (float*)(ws + 196608);    // 64 KB slot (16384 fp32)
    bf16* wt = (bf16*)(ws + 262144);
    bf16* wt_g1      = wt;                   // 3 x [1024][256]  (nw-folded inp^T | D^T)
    bf16* wt_g3      = wt + 786432;          // 3 x [fc1^T | fc2⊕fc3]
    bf16* wt_convlin = wt + 2359296;
    bf16* wt_out     = wt + 3145728;
    bf16* wt_proj    = wt + 3538944;
    bf16* wt_conv    = wt + 3604480;         // 3 x [3][512][512]
    bf16* xpT = (bf16*)(ws + 12189696);      // [32][528][512]
    const size_t POOLB = 16777216;
    bf16* pool[4] = {
        (bf16*)(ws + 29491200),
        (bf16*)(ws + 29491200 + POOLB),
        (bf16*)(ws + 29491200 + 2 * POOLB),
        (bf16*)(ws + 29491200 + 3 * POOLB),
    };
    float* out = (float*)d_out;

    // ---- single merged prepack (weights + conv + pads + CBv zero) ----
    P8 p;
    p.s[0] = inp_W;  p.d[0] = wt_g1;
    p.s[1] = D_W;    p.d[1] = wt_g1 + 131072;
    p.s[2] = fc1_W;  p.d[2] = wt_g3;
    p.s[3] = fc2_W;  p.d[3] = wt_g3 + 262144;
    p.s[4] = fc3_W;  p.d[4] = wt_g3 + 262144;
    p.s[5] = convlin_W; p.d[5] = wt_convlin;
    p.s[6] = out_W;  p.d[6] = wt_out;
    p.s[7] = proj_W; p.d[7] = wt_proj;
    int convBlocks = (CONVN + 32768 + MROWS + 255) / 256;
    prepack_all_kernel<<<MTILES + convBlocks, 256, 0, stream>>>(
        p, norm_w, conv_W, wt_conv, xpT, CBv);

    // ---- stats + build: raw x -> pool[0].lo, rms scale -> SCL ----
    buildx_kernel<<<256, 256, 0, stream>>>(x_enc, x_mark, MEANS, STDEV, pool[0], SCL);

    // 4-pool rotation
    int ia = 0, ico = 1, ires = 2, iout = 3;
    for (int i = 0; i < 3; i++) {
        bf16* A  = pool[ia];
        bf16* XCO = pool[ico];
        bf16* XRES = pool[ires];
        bf16* OUTP = pool[iout];

        // [xp|xres] = (x*scl) @ [nw∘inp | nw∘D] + b : xp -> xpT^T, xres -> XRES
        mgemm_kernel<1><<<dim3(128, 8), 256, 0, stream>>>(
            A, wt_g1 + (size_t)i * 262144, inp_b + i * CT2, D_b + i * CT2, SCL,
            xpT, XRES, 256, 1024);
        // xc = silu(conv(xp)) -> A ; zeroes CBv
        conv_mfma_kernel<<<512, 256, 0, stream>>>(wt_conv + (size_t)i * 786432, xpT,
                                                  conv_b + i * CF, A, CBv);
        // xco = xc @ convlin + b -> XCO
        mgemm_kernel<0><<<dim3(128, 4), 256, 0, stream>>>(
            A, wt_convlin + (size_t)i * 262144, convlin_b + i * CT2, nullptr, nullptr,
            XCO, nullptr, 512, 512);
        // cb atomics
        cbgemm_kernel<<<dim3(128, 4), 256, 0, stream>>>(
            XCO, wt_g3 + (size_t)i * 524288 + 262144, fc2_b + i * CT, fc3_b + i * CT, CBv);
        // g = gate(fc1, xco, cb, xres) -> A
        fc1gate_kernel<<<dim3(128, 4), 256, 0, stream>>>(
            XCO, wt_g3 + (size_t)i * 524288, fc1_b + i * CT2, CBv, XRES, A);
        // x_next = g @ out_W + b -> OUTP.lo ; scl -> SCL
        gemm_scl_kernel<<<256, 256, 0, stream>>>(
            A, wt_out + (size_t)i * 131072, out_b + i * CT, OUTP, SCL);

        int na = iout, nco = ia, nres = ico, nout = ires;
        ia = na; ico = nco; ires = nres; iout = nout;
    }

    // x_final in pool[ia].lo. dec = x @ proj_W + b, de-norm + transpose to out
    proj_out_kernel<<<dim3(128, 2), 256, 0, stream>>>(
        pool[ia], wt_proj, proj_b, MEANS, STDEV, out);
}